// Round 1
// baseline (6262.851 us; speedup 1.0000x reference)
//
#include <hip/hip_runtime.h>

#define N_NODES 100000
#define E_EDGES 1600000
#define F_IN    64
#define H_DIM   128
#define R_REL   20
#define G_GRAPHS 64
#define C_CLASSES 10
#define L_LAYERS 2
#define BN_EPS  1e-5f

// ============================================================
// Edge preprocessing
// ============================================================

// cnt[dst*R + type] += 1  (for mean normalization), plus global per-type histogram
__global__ void count_kernel(const int* __restrict__ ei, const int* __restrict__ et,
                             int* __restrict__ cnt, int* __restrict__ type_count) {
    __shared__ int lc[R_REL];
    if (threadIdx.x < R_REL) lc[threadIdx.x] = 0;
    __syncthreads();
    for (int e = blockIdx.x * blockDim.x + threadIdx.x; e < E_EDGES;
         e += gridDim.x * blockDim.x) {
        int t = et[e];
        int d = ei[E_EDGES + e];          // dst row
        atomicAdd(&cnt[(size_t)d * R_REL + t], 1);
        atomicAdd(&lc[t], 1);
    }
    __syncthreads();
    if (threadIdx.x < R_REL) atomicAdd(&type_count[threadIdx.x], lc[threadIdx.x]);
}

// serial exclusive scan over R=20 buckets
__global__ void scan_kernel(const int* __restrict__ type_count,
                            int* __restrict__ type_off, int* __restrict__ cursor) {
    if (threadIdx.x == 0) {
        int off = 0;
        for (int r = 0; r < R_REL; ++r) {
            type_off[r] = off;
            cursor[r]   = off;
            off += type_count[r];
        }
        type_off[R_REL] = off;
    }
}

// counting-sort edges by relation; also precompute per-edge norm
__global__ void bucket_kernel(const int* __restrict__ ei, const int* __restrict__ et,
                              const int* __restrict__ cnt, int* __restrict__ cursor,
                              int* __restrict__ esrc, int* __restrict__ edst,
                              float* __restrict__ enorm) {
    __shared__ int lc[R_REL];
    __shared__ int lbase[R_REL];
    int t = threadIdx.x;
    if (t < R_REL) lc[t] = 0;
    __syncthreads();

    int e0 = blockIdx.x * 1024;
    int myt[4], rank[4], s[4], d[4];
#pragma unroll
    for (int j = 0; j < 4; ++j) {
        int e = e0 + t + j * 256;
        if (e < E_EDGES) {
            myt[j] = et[e];
            s[j]   = ei[e];
            d[j]   = ei[E_EDGES + e];
            rank[j] = atomicAdd(&lc[myt[j]], 1);
        } else {
            myt[j] = -1;
        }
    }
    __syncthreads();
    if (t < R_REL) lbase[t] = atomicAdd(&cursor[t], lc[t]);
    __syncthreads();
#pragma unroll
    for (int j = 0; j < 4; ++j) {
        if (myt[j] >= 0) {
            int pos = lbase[myt[j]] + rank[j];
            esrc[pos] = s[j];
            edst[pos] = d[j];
            enorm[pos] = 1.0f / fmaxf((float)cnt[(size_t)d[j] * R_REL + myt[j]], 1.0f);
        }
    }
}

// ============================================================
// Generic tiled GEMM: Out[M,128] = A[M or gathered, K] @ W[K,128]
// GATHER: A rows via gidx; SCATTER: atomicAdd into Out[didx[row]] scaled by rownorm
// ============================================================
template<int K, bool GATHER, bool SCATTER, bool RELU, bool HASBIAS>
__global__ __launch_bounds__(256)
void gemm_kernel(const float* __restrict__ A, const float* __restrict__ Wg,
                 const float* __restrict__ bias, float* __restrict__ Out,
                 int Mconst, const int* __restrict__ boundsp,
                 const int* __restrict__ gidx, const int* __restrict__ didx,
                 const float* __restrict__ rownorm) {
    constexpr int BM = 32;
    constexpr int AS = 36;   // padded stride: conflict-free + float4-aligned
    constexpr int BK = 64;
    __shared__ float W_s[BK * H_DIM];      // 32 KB
    __shared__ float A_s[K * AS];          // 18 KB (K=128) / 9 KB (K=64)

    const float* W = Wg + (size_t)blockIdx.y * K * H_DIM;
    int mb, me;
    if (SCATTER) { mb = boundsp[blockIdx.y]; me = boundsp[blockIdx.y + 1]; }
    else         { mb = 0;                   me = Mconst; }

    int tx = threadIdx.x & 31;   // 32 col-groups
    int ty = threadIdx.x >> 5;   // 8 row-groups
    int c0 = tx * 4;
    int r0 = ty * 4;

    for (int tb = mb + blockIdx.x * BM; tb < me; tb += gridDim.x * BM) {
        __syncthreads();  // protect A_s/W_s from previous iteration readers
        // stage A tile (transposed, padded): A_s[k*AS + row]
        for (int i = threadIdx.x; i < BM * K; i += 256) {
            int row = i / K;
            int k   = i % K;
            int grow = tb + row;
            float v = 0.f;
            if (grow < me) {
                int g = GATHER ? gidx[grow] : grow;
                v = A[(size_t)g * K + k];
            }
            A_s[k * AS + row] = v;
        }

        float acc[4][4];
#pragma unroll
        for (int a = 0; a < 4; ++a)
#pragma unroll
            for (int b = 0; b < 4; ++b) acc[a][b] = 0.f;

#pragma unroll
        for (int kt = 0; kt < K / BK; ++kt) {
            __syncthreads();   // A_s ready / previous W_s readers done
            for (int i = threadIdx.x; i < BK * H_DIM; i += 256)
                W_s[i] = W[kt * BK * H_DIM + i];
            __syncthreads();
#pragma unroll 8
            for (int kk = 0; kk < BK; ++kk) {
                int k = kt * BK + kk;
                float4 av = *(const float4*)&A_s[k * AS + r0];
                float4 wv = *(const float4*)&W_s[kk * H_DIM + c0];
                float a4[4] = {av.x, av.y, av.z, av.w};
                float w4[4] = {wv.x, wv.y, wv.z, wv.w};
#pragma unroll
                for (int a = 0; a < 4; ++a)
#pragma unroll
                    for (int b = 0; b < 4; ++b)
                        acc[a][b] = fmaf(a4[a], w4[b], acc[a][b]);
            }
        }

        if (SCATTER) {
#pragma unroll
            for (int a = 0; a < 4; ++a) {
                int grow = tb + r0 + a;
                if (grow < me) {
                    int dd = didx[grow];
                    float sc = rownorm[grow];
                    float* op = Out + (size_t)dd * H_DIM + c0;
                    atomicAdd(op + 0, acc[a][0] * sc);
                    atomicAdd(op + 1, acc[a][1] * sc);
                    atomicAdd(op + 2, acc[a][2] * sc);
                    atomicAdd(op + 3, acc[a][3] * sc);
                }
            }
        } else {
#pragma unroll
            for (int a = 0; a < 4; ++a) {
                int grow = tb + r0 + a;
                if (grow < me) {
                    float4 o;
                    o.x = acc[a][0]; o.y = acc[a][1]; o.z = acc[a][2]; o.w = acc[a][3];
                    if (HASBIAS) {
                        o.x += bias[c0 + 0]; o.y += bias[c0 + 1];
                        o.z += bias[c0 + 2]; o.w += bias[c0 + 3];
                    }
                    if (RELU) {
                        o.x = fmaxf(o.x, 0.f); o.y = fmaxf(o.y, 0.f);
                        o.z = fmaxf(o.z, 0.f); o.w = fmaxf(o.w, 0.f);
                    }
                    *(float4*)&Out[(size_t)grow * H_DIM + c0] = o;
                }
            }
        }
    }
}

// ============================================================
// BatchNorm (training-mode batch stats) + ReLU
// ============================================================
__global__ void bn_reduce(const float* __restrict__ X, float* __restrict__ sums) {
    int col  = threadIdx.x & 127;
    int half = threadIdx.x >> 7;
    float s = 0.f, ss = 0.f;
    for (int row = blockIdx.x * 2 + half; row < N_NODES; row += gridDim.x * 2) {
        float v = X[(size_t)row * H_DIM + col];
        s += v;
        ss += v * v;
    }
    atomicAdd(&sums[col], s);
    atomicAdd(&sums[H_DIM + col], ss);
}

__global__ void bn_apply(const float* __restrict__ X, const float* __restrict__ sums,
                         const float* __restrict__ gg, const float* __restrict__ bb,
                         float* __restrict__ Hout) {
    __shared__ float sc[H_DIM], sh[H_DIM];
    if (threadIdx.x < H_DIM) {
        float mean = sums[threadIdx.x] * (1.0f / N_NODES);
        float var  = sums[H_DIM + threadIdx.x] * (1.0f / N_NODES) - mean * mean;
        float inv  = rsqrtf(var + BN_EPS) * gg[threadIdx.x];
        sc[threadIdx.x] = inv;
        sh[threadIdx.x] = bb[threadIdx.x] - mean * inv;
    }
    __syncthreads();
    int total = N_NODES * (H_DIM / 4);
    for (int idx = blockIdx.x * 256 + threadIdx.x; idx < total; idx += gridDim.x * 256) {
        float4 v = ((const float4*)X)[idx];
        int c = (idx & 31) << 2;
        float4 o;
        o.x = fmaxf(v.x * sc[c + 0] + sh[c + 0], 0.f);
        o.y = fmaxf(v.y * sc[c + 1] + sh[c + 1], 0.f);
        o.z = fmaxf(v.z * sc[c + 2] + sh[c + 2], 0.f);
        o.w = fmaxf(v.w * sc[c + 3] + sh[c + 3], 0.f);
        ((float4*)Hout)[idx] = o;
    }
}

// ============================================================
// Global mean pool (batch is sorted -> register run-length accumulate)
// ============================================================
__global__ void pool_kernel(const float* __restrict__ Hf, const int* __restrict__ batch,
                            float* __restrict__ pool, float* __restrict__ pcnt) {
    int col  = threadIdx.x & 127;
    int half = threadIdx.x >> 7;
    int chunk = (N_NODES + gridDim.x - 1) / gridDim.x;
    int start = blockIdx.x * chunk;
    int end   = min(N_NODES, start + chunk);
    int curg = -1;
    float acc = 0.f, c = 0.f;
    for (int row = start + half; row < end; row += 2) {
        int g = batch[row];
        if (g != curg) {
            if (curg >= 0) {
                atomicAdd(&pool[curg * H_DIM + col], acc);
                if (col == 0) atomicAdd(&pcnt[curg], c);
            }
            curg = g; acc = 0.f; c = 0.f;
        }
        acc += Hf[(size_t)row * H_DIM + col];
        c += 1.f;
    }
    if (curg >= 0) {
        atomicAdd(&pool[curg * H_DIM + col], acc);
        if (col == 0) atomicAdd(&pcnt[curg], c);
    }
}

__global__ void logits_kernel(const float* __restrict__ pool, const float* __restrict__ pcnt,
                              const float* __restrict__ w_out, const float* __restrict__ b_out,
                              float* __restrict__ out) {
    int g = blockIdx.x;
    __shared__ float p[H_DIM];
    float cnt = fmaxf(pcnt[g], 1.0f);
    p[threadIdx.x] = pool[g * H_DIM + threadIdx.x] / cnt;
    __syncthreads();
    if (threadIdx.x < C_CLASSES) {
        float acc = b_out[threadIdx.x];
        for (int k = 0; k < H_DIM; ++k)
            acc += p[k] * w_out[k * C_CLASSES + threadIdx.x];
        out[g * C_CLASSES + threadIdx.x] = 1.0f / (1.0f + expf(-acc));
    }
}

// ============================================================
// Host launch
// ============================================================
static inline size_t align256(size_t x) { return (x + 255) & ~(size_t)255; }

extern "C" void kernel_launch(void* const* d_in, const int* in_sizes, int n_in,
                              void* d_out, int out_size, void* d_ws, size_t ws_size,
                              hipStream_t stream) {
    const float* x      = (const float*)d_in[0];
    const int*   ei     = (const int*)d_in[1];
    const int*   et     = (const int*)d_in[2];
    const int*   batch  = (const int*)d_in[3];
    const float* w_in   = (const float*)d_in[4];
    const float* b_in   = (const float*)d_in[5];
    const float* rel_w  = (const float*)d_in[6];
    const float* root_w = (const float*)d_in[7];
    const float* conv_b = (const float*)d_in[8];
    const float* bn_g   = (const float*)d_in[9];
    const float* bn_b   = (const float*)d_in[10];
    const float* w_out  = (const float*)d_in[11];
    const float* b_out  = (const float*)d_in[12];
    float* out = (float*)d_out;

    char* ws = (char*)d_ws;
    size_t off = 0;
    float* h    = (float*)(ws + off); off += align256((size_t)N_NODES * H_DIM * 4);
    float* outb = (float*)(ws + off); off += align256((size_t)N_NODES * H_DIM * 4);
    int*   cnt  = (int*)(ws + off);   off += align256((size_t)N_NODES * R_REL * 4);
    int*   e_src = (int*)(ws + off);  off += align256((size_t)E_EDGES * 4);
    int*   e_dst = (int*)(ws + off);  off += align256((size_t)E_EDGES * 4);
    float* e_norm = (float*)(ws + off); off += align256((size_t)E_EDGES * 4);
    int*   type_count = (int*)(ws + off); off += 256;
    int*   type_off   = (int*)(ws + off); off += 256;
    int*   cursor     = (int*)(ws + off); off += 256;
    float* bn_sums    = (float*)(ws + off); off += align256(2 * H_DIM * 4);
    float* pool       = (float*)(ws + off); off += align256((size_t)G_GRAPHS * H_DIM * 4);
    float* pcnt       = (float*)(ws + off); off += 256;

    // ---- edge preprocessing ----
    hipMemsetAsync(cnt, 0, (size_t)N_NODES * R_REL * 4, stream);
    hipMemsetAsync(type_count, 0, 256, stream);
    count_kernel<<<1024, 256, 0, stream>>>(ei, et, cnt, type_count);
    scan_kernel<<<1, 64, 0, stream>>>(type_count, type_off, cursor);
    bucket_kernel<<<(E_EDGES + 1023) / 1024, 256, 0, stream>>>(ei, et, cnt, cursor,
                                                               e_src, e_dst, e_norm);

    // ---- input MLP: h = relu(x @ w_in + b_in) ----
    gemm_kernel<F_IN, false, false, true, true><<<dim3(640, 1), 256, 0, stream>>>(
        x, w_in, b_in, h, N_NODES, nullptr, nullptr, nullptr, nullptr);

    // ---- RGCN layers ----
    for (int l = 0; l < L_LAYERS; ++l) {
        // root/self transform + bias (dense store initializes outb)
        gemm_kernel<H_DIM, false, false, false, true><<<dim3(640, 1), 256, 0, stream>>>(
            h, root_w + (size_t)l * H_DIM * H_DIM, conv_b + (size_t)l * H_DIM, outb,
            N_NODES, nullptr, nullptr, nullptr, nullptr);
        // fused per-relation gathered GEMM + scatter: outb[dst] += (h[src] @ W_r) * norm
        gemm_kernel<H_DIM, true, true, false, false><<<dim3(256, R_REL), 256, 0, stream>>>(
            h, rel_w + (size_t)l * R_REL * H_DIM * H_DIM, nullptr, outb,
            0, type_off, e_src, e_dst, e_norm);
        // batchnorm + relu -> h
        hipMemsetAsync(bn_sums, 0, 2 * H_DIM * 4, stream);
        bn_reduce<<<512, 256, 0, stream>>>(outb, bn_sums);
        bn_apply<<<2048, 256, 0, stream>>>(outb, bn_sums,
                                           bn_g + (size_t)l * H_DIM,
                                           bn_b + (size_t)l * H_DIM, h);
    }

    // ---- global mean pool + classifier ----
    hipMemsetAsync(pool, 0, (size_t)G_GRAPHS * H_DIM * 4, stream);
    hipMemsetAsync(pcnt, 0, 256, stream);
    pool_kernel<<<512, 256, 0, stream>>>(h, batch, pool, pcnt);
    logits_kernel<<<G_GRAPHS, 128, 0, stream>>>(pool, pcnt, w_out, b_out, out);
}

// Round 2
// 2018.928 us; speedup vs baseline: 3.1021x; 3.1021x over previous
//
#include <hip/hip_runtime.h>
#include <hip/hip_bf16.h>

#define N_NODES 100000
#define E_EDGES 1600000
#define F_IN    64
#define H_DIM   128
#define R_REL   20
#define G_GRAPHS 64
#define C_CLASSES 10
#define L_LAYERS 2
#define BN_EPS  1e-5f

typedef unsigned short u16;
typedef unsigned int   u32;
typedef __attribute__((ext_vector_type(8))) short short8;
typedef __attribute__((ext_vector_type(4))) float f32x4;

static __device__ __forceinline__ float bf2f(u16 u) {
    u32 b = ((u32)u) << 16;
    return __builtin_bit_cast(float, b);
}
static __device__ __forceinline__ u16 f2bf(float f) {
    u32 x = __builtin_bit_cast(u32, f);
    u32 r = x + 0x7fff + ((x >> 16) & 1);   // RNE; inputs finite
    return (u16)(r >> 16);
}

// ============================================================
// Edge preprocessing
// ============================================================

__global__ void count_kernel(const int* __restrict__ ei, const int* __restrict__ et,
                             int* __restrict__ cnt, int* __restrict__ dst_cnt,
                             int* __restrict__ type_count) {
    __shared__ int lc[R_REL];
    if (threadIdx.x < R_REL) lc[threadIdx.x] = 0;
    __syncthreads();
    for (int e = blockIdx.x * blockDim.x + threadIdx.x; e < E_EDGES;
         e += gridDim.x * blockDim.x) {
        int t = et[e];
        int d = ei[E_EDGES + e];
        atomicAdd(&cnt[(size_t)d * R_REL + t], 1);
        atomicAdd(&dst_cnt[d], 1);
        atomicAdd(&lc[t], 1);
    }
    __syncthreads();
    if (threadIdx.x < R_REL) atomicAdd(&type_count[threadIdx.x], lc[threadIdx.x]);
}

__global__ void scanR_kernel(const int* __restrict__ type_count,
                             int* __restrict__ type_off, int* __restrict__ cursor) {
    if (threadIdx.x == 0) {
        int off = 0;
        for (int r = 0; r < R_REL; ++r) {
            type_off[r] = off;
            cursor[r]   = off;
            off += type_count[r];
        }
        type_off[R_REL] = off;
    }
}

// hierarchical exclusive scan of dst_cnt[N] -> dst_off  (1024 items / block)
__global__ void scan1_kernel(const int* __restrict__ in, int* __restrict__ out,
                             int* __restrict__ partial) {
    __shared__ int s[256];
    int t = threadIdx.x;
    int base = blockIdx.x * 1024;
    int v[4]; int sum = 0;
#pragma unroll
    for (int j = 0; j < 4; ++j) {
        int i = base + t * 4 + j;
        v[j] = (i < N_NODES) ? in[i] : 0;
        sum += v[j];
    }
    s[t] = sum;
    __syncthreads();
    for (int off = 1; off < 256; off <<= 1) {
        int x = (t >= off) ? s[t - off] : 0;
        __syncthreads();
        s[t] += x;
        __syncthreads();
    }
    if (t == 255) partial[blockIdx.x] = s[255];
    int run = s[t] - sum;   // exclusive prefix of this thread's chunk
#pragma unroll
    for (int j = 0; j < 4; ++j) {
        int i = base + t * 4 + j;
        if (i < N_NODES) out[i] = run;
        run += v[j];
    }
}

__global__ void scan2_kernel(int* __restrict__ partial, int nb) {
    __shared__ int s[128];
    int t = threadIdx.x;
    int v = (t < nb) ? partial[t] : 0;
    s[t] = v;
    __syncthreads();
    for (int off = 1; off < 128; off <<= 1) {
        int x = (t >= off) ? s[t - off] : 0;
        __syncthreads();
        s[t] += x;
        __syncthreads();
    }
    if (t < nb) partial[t] = s[t] - v;   // exclusive block bases
}

__global__ void scan3_kernel(int* __restrict__ dst_off, const int* __restrict__ partial) {
    for (int i = blockIdx.x * blockDim.x + threadIdx.x; i < N_NODES;
         i += gridDim.x * blockDim.x)
        dst_off[i] += partial[i >> 10];
    if (blockIdx.x == 0 && threadIdx.x == 0) dst_off[N_NODES] = E_EDGES;
}

// counting-sort by relation; per-edge: src gather idx, norm, and either
// dst-sorted output slot q (fast) or raw dst (fallback)
__global__ void bucket_kernel(const int* __restrict__ ei, const int* __restrict__ et,
                              const int* __restrict__ cnt, const int* __restrict__ dst_off,
                              int* __restrict__ dst_cur, int* __restrict__ cursor,
                              int* __restrict__ esrc, int* __restrict__ eq,
                              float* __restrict__ enorm, int fastmode) {
    __shared__ int lc[R_REL];
    __shared__ int lbase[R_REL];
    int t = threadIdx.x;
    if (t < R_REL) lc[t] = 0;
    __syncthreads();

    int e0 = blockIdx.x * 1024;
    int myt[4], rank[4], s[4], d[4];
#pragma unroll
    for (int j = 0; j < 4; ++j) {
        int e = e0 + t + j * 256;
        if (e < E_EDGES) {
            myt[j] = et[e];
            s[j]   = ei[e];
            d[j]   = ei[E_EDGES + e];
            rank[j] = atomicAdd(&lc[myt[j]], 1);
        } else {
            myt[j] = -1;
        }
    }
    __syncthreads();
    if (t < R_REL) lbase[t] = atomicAdd(&cursor[t], lc[t]);
    __syncthreads();
#pragma unroll
    for (int j = 0; j < 4; ++j) {
        if (myt[j] >= 0) {
            int pos = lbase[myt[j]] + rank[j];
            esrc[pos]  = s[j];
            enorm[pos] = 1.0f / fmaxf((float)cnt[(size_t)d[j] * R_REL + myt[j]], 1.0f);
            eq[pos] = fastmode ? (dst_off[d[j]] + atomicAdd(&dst_cur[d[j]], 1)) : d[j];
        }
    }
}

// ============================================================
// Weight pack: fp32 [K,128] -> bf16 MFMA-frag order
// Wp[((kt*8+ct)*64 + l)*8 + j] = W[(kt*32 + (l>>4)*8 + j)*128 + ct*16 + (l&15)]
// ============================================================
template<int K>
__global__ void pack_w(const float* __restrict__ W, u16* __restrict__ Wp) {
    const float* w = W + (size_t)blockIdx.x * K * H_DIM;
    u16* p = Wp + (size_t)blockIdx.x * K * H_DIM;
    for (int o = threadIdx.x; o < K * H_DIM; o += blockDim.x) {
        int j  = o & 7;
        int l  = (o >> 3) & 63;
        int ct = (o >> 9) & 7;
        int kt = o >> 12;
        int k  = kt * 32 + (l >> 4) * 8 + j;
        int n  = ct * 16 + (l & 15);
        p[o] = f2bf(w[(size_t)k * H_DIM + n]);
    }
}

__global__ void cvt_bf16_kernel(const float* __restrict__ in, u16* __restrict__ out, int n4) {
    for (int i = blockIdx.x * blockDim.x + threadIdx.x; i < n4;
         i += gridDim.x * blockDim.x) {
        float4 v = ((const float4*)in)[i];
        ushort4 o;
        o.x = f2bf(v.x); o.y = f2bf(v.y); o.z = f2bf(v.z); o.w = f2bf(v.w);
        ((ushort4*)out)[i] = o;
    }
}

// ============================================================
// MFMA GEMM: Out[M,128] = A[M(gathered),K]_bf16 @ W[K,128]_bf16(packed)
//  PERM:  bf16 store to row qpos[row], scaled by rownorm  (edge message GEMM)
//  ATOMIC: fp32 atomicAdd to Out[qpos[row]] (fallback edge GEMM)
//  else:  dense output (bf16 via OUTBF16, or fp32), +bias, optional relu
// block = 256 (4 waves); tile 64 rows x 128 cols; wave w owns rows [16w,16w+16)
// ============================================================
template<int K, bool GATHER, bool PERM, bool RELU, bool HASBIAS, bool OUTBF16, bool ATOMIC>
__global__ __launch_bounds__(256)
void mfma_gemm(const u16* __restrict__ A, const u16* __restrict__ Wp,
               const float* __restrict__ bias, void* __restrict__ OutV,
               int Mconst, const int* __restrict__ boundsp,
               const int* __restrict__ gidx, const int* __restrict__ qpos,
               const float* __restrict__ rownorm) {
    constexpr int CH = K / 8;                  // 16B chunks per A row
    __shared__ u16 Ws[K * H_DIM];              // packed weights (frag order)
    __shared__ u16 As[64 * H_DIM];             // A stage (64 x K, swizzled); reused as repack buf

    const u16* W = Wp + (size_t)blockIdx.y * K * H_DIM;
    int mb, me;
    if (PERM || ATOMIC) { mb = boundsp[blockIdx.y]; me = boundsp[blockIdx.y + 1]; }
    else                { mb = 0;                   me = Mconst; }

    // load packed W to LDS (visible after first loop-top barrier)
    for (int o = threadIdx.x; o < K * H_DIM / 8; o += 256)
        ((short8*)Ws)[o] = ((const short8*)W)[o];

    const int lane = threadIdx.x & 63;
    const int wave = threadIdx.x >> 6;
    const int l15  = lane & 15;
    const int kgrp = lane >> 4;
    const int arow = wave * 16 + l15;

    for (int tb = mb + blockIdx.x * 64; tb < me; tb += gridDim.x * 64) {
        __syncthreads();
        // stage A tile: As[row*K + (chunk^(row&7))*8]
        for (int o = threadIdx.x; o < 64 * CH; o += 256) {
            int row = o / CH, cc = o % CH;
            int grow = tb + row;
            short8 v = {0,0,0,0,0,0,0,0};
            if (grow < me) {
                int g = GATHER ? gidx[grow] : grow;
                v = *(const short8*)&A[(size_t)g * K + cc * 8];
            }
            *(short8*)&As[row * K + ((cc ^ (row & 7)) * 8)] = v;
        }
        __syncthreads();

        f32x4 acc[8];
#pragma unroll
        for (int i = 0; i < 8; ++i) {
            acc[i][0] = 0.f; acc[i][1] = 0.f; acc[i][2] = 0.f; acc[i][3] = 0.f;
        }
#pragma unroll
        for (int kt = 0; kt < K / 32; ++kt) {
            short8 af = *(const short8*)&As[arow * K + (((kt * 4 + kgrp) ^ (arow & 7)) * 8)];
#pragma unroll
            for (int ct = 0; ct < 8; ++ct) {
                short8 bf = *(const short8*)&Ws[(((kt * 8 + ct) * 64) + lane) * 8];
                acc[ct] = __builtin_amdgcn_mfma_f32_16x16x32_bf16(af, bf, acc[ct], 0, 0, 0);
            }
        }

        if (OUTBF16) {
            __syncthreads();   // done reading As fragments
            float rn[4];
            if (PERM) {
#pragma unroll
                for (int r = 0; r < 4; ++r) {
                    int grow = tb + wave * 16 + kgrp * 4 + r;
                    rn[r] = (grow < me) ? rownorm[grow] : 0.f;
                }
            }
#pragma unroll
            for (int ct = 0; ct < 8; ++ct) {
#pragma unroll
                for (int r = 0; r < 4; ++r) {
                    int row = wave * 16 + kgrp * 4 + r;
                    int col = ct * 16 + l15;
                    float v = acc[ct][r];
                    if (HASBIAS) v += bias[col];
                    if (PERM)    v *= rn[r];
                    if (RELU)    v = fmaxf(v, 0.f);
                    // swizzled repack: chunk (col>>3) ^ (row&7)
                    As[row * H_DIM + ((((col >> 3) ^ (row & 7)) << 3) | (col & 7))] = f2bf(v);
                }
            }
            __syncthreads();
            u16* Out = (u16*)OutV;
            for (int o = threadIdx.x; o < 64 * 16; o += 256) {
                int row = o >> 4, cc = o & 15;
                int grow = tb + row;
                if (grow < me) {
                    int q = PERM ? qpos[grow] : grow;
                    *(short8*)&Out[(size_t)q * H_DIM + cc * 8] =
                        *(const short8*)&As[row * H_DIM + ((cc ^ (row & 7)) << 3)];
                }
            }
        } else if (ATOMIC) {
            float* Out = (float*)OutV;
#pragma unroll
            for (int ct = 0; ct < 8; ++ct) {
#pragma unroll
                for (int r = 0; r < 4; ++r) {
                    int grow = tb + wave * 16 + kgrp * 4 + r;
                    if (grow < me) {
                        int dd = qpos[grow];
                        atomicAdd(&Out[(size_t)dd * H_DIM + ct * 16 + l15],
                                  acc[ct][r] * rownorm[grow]);
                    }
                }
            }
        } else {
            float* Out = (float*)OutV;
#pragma unroll
            for (int ct = 0; ct < 8; ++ct) {
#pragma unroll
                for (int r = 0; r < 4; ++r) {
                    int grow = tb + wave * 16 + kgrp * 4 + r;
                    if (grow < me) {
                        float v = acc[ct][r];
                        if (HASBIAS) v += bias[ct * 16 + l15];
                        if (RELU)    v = fmaxf(v, 0.f);
                        Out[(size_t)grow * H_DIM + ct * 16 + l15] = v;
                    }
                }
            }
        }
    }
}

// ============================================================
// Segment sum over dst-sorted messages: outb[d] += sum(m[dst_off[d]:dst_off[d+1]])
// one wave per dst; owner-exclusive (no atomics)
// ============================================================
__global__ void seg_reduce(const u16* __restrict__ m, const int* __restrict__ dst_off,
                           float* __restrict__ outb) {
    int wave = threadIdx.x >> 6, lane = threadIdx.x & 63;
    int d0 = blockIdx.x * 64;
    for (int dd = wave; dd < 64; dd += 4) {
        int d = d0 + dd;
        if (d >= N_NODES) break;
        int s = dst_off[d], e = dst_off[d + 1];
        if (s == e) continue;
        float a0 = 0.f, a1 = 0.f;
        int i = s;
        for (; i + 1 < e; i += 2) {
            u32 v0 = *(const u32*)&m[(size_t)i * H_DIM + lane * 2];
            u32 v1 = *(const u32*)&m[(size_t)(i + 1) * H_DIM + lane * 2];
            a0 += bf2f((u16)(v0 & 0xffff)) + bf2f((u16)(v1 & 0xffff));
            a1 += bf2f((u16)(v0 >> 16))    + bf2f((u16)(v1 >> 16));
        }
        if (i < e) {
            u32 v0 = *(const u32*)&m[(size_t)i * H_DIM + lane * 2];
            a0 += bf2f((u16)(v0 & 0xffff));
            a1 += bf2f((u16)(v0 >> 16));
        }
        float* op = &outb[(size_t)d * H_DIM + lane * 2];
        op[0] += a0;
        op[1] += a1;
    }
}

// ============================================================
// BatchNorm + ReLU -> bf16 h
// ============================================================
__global__ void bn_reduce(const float* __restrict__ X, float* __restrict__ sums) {
    int col  = threadIdx.x & 127;
    int half = threadIdx.x >> 7;
    float s = 0.f, ss = 0.f;
    for (int row = blockIdx.x * 2 + half; row < N_NODES; row += gridDim.x * 2) {
        float v = X[(size_t)row * H_DIM + col];
        s += v; ss += v * v;
    }
    atomicAdd(&sums[col], s);
    atomicAdd(&sums[H_DIM + col], ss);
}

__global__ void bn_apply(const float* __restrict__ X, const float* __restrict__ sums,
                         const float* __restrict__ gg, const float* __restrict__ bb,
                         u16* __restrict__ Hout) {
    __shared__ float sc[H_DIM], sh[H_DIM];
    if (threadIdx.x < H_DIM) {
        float mean = sums[threadIdx.x] * (1.0f / N_NODES);
        float var  = sums[H_DIM + threadIdx.x] * (1.0f / N_NODES) - mean * mean;
        float inv  = rsqrtf(var + BN_EPS) * gg[threadIdx.x];
        sc[threadIdx.x] = inv;
        sh[threadIdx.x] = bb[threadIdx.x] - mean * inv;
    }
    __syncthreads();
    int total = N_NODES * (H_DIM / 4);
    for (int idx = blockIdx.x * 256 + threadIdx.x; idx < total; idx += gridDim.x * 256) {
        float4 v = ((const float4*)X)[idx];
        int c = (idx & 31) << 2;
        ushort4 o;
        o.x = f2bf(fmaxf(v.x * sc[c + 0] + sh[c + 0], 0.f));
        o.y = f2bf(fmaxf(v.y * sc[c + 1] + sh[c + 1], 0.f));
        o.z = f2bf(fmaxf(v.z * sc[c + 2] + sh[c + 2], 0.f));
        o.w = f2bf(fmaxf(v.w * sc[c + 3] + sh[c + 3], 0.f));
        ((ushort4*)Hout)[idx] = o;
    }
}

// ============================================================
// Pool + classifier
// ============================================================
__global__ void pool_kernel(const u16* __restrict__ Hf, const int* __restrict__ batch,
                            float* __restrict__ pool, float* __restrict__ pcnt) {
    int col  = threadIdx.x & 127;
    int half = threadIdx.x >> 7;
    int chunk = (N_NODES + gridDim.x - 1) / gridDim.x;
    int start = blockIdx.x * chunk;
    int end   = min(N_NODES, start + chunk);
    int curg = -1;
    float acc = 0.f, c = 0.f;
    for (int row = start + half; row < end; row += 2) {
        int g = batch[row];
        if (g != curg) {
            if (curg >= 0) {
                atomicAdd(&pool[curg * H_DIM + col], acc);
                if (col == 0) atomicAdd(&pcnt[curg], c);
            }
            curg = g; acc = 0.f; c = 0.f;
        }
        acc += bf2f(Hf[(size_t)row * H_DIM + col]);
        c += 1.f;
    }
    if (curg >= 0) {
        atomicAdd(&pool[curg * H_DIM + col], acc);
        if (col == 0) atomicAdd(&pcnt[curg], c);
    }
}

__global__ void logits_kernel(const float* __restrict__ pool, const float* __restrict__ pcnt,
                              const float* __restrict__ w_out, const float* __restrict__ b_out,
                              float* __restrict__ out) {
    int g = blockIdx.x;
    __shared__ float p[H_DIM];
    float cnt = fmaxf(pcnt[g], 1.0f);
    p[threadIdx.x] = pool[g * H_DIM + threadIdx.x] / cnt;
    __syncthreads();
    if (threadIdx.x < C_CLASSES) {
        float acc = b_out[threadIdx.x];
        for (int k = 0; k < H_DIM; ++k)
            acc += p[k] * w_out[k * C_CLASSES + threadIdx.x];
        out[g * C_CLASSES + threadIdx.x] = 1.0f / (1.0f + expf(-acc));
    }
}

// ============================================================
// Host launch
// ============================================================
static inline size_t align256(size_t x) { return (x + 255) & ~(size_t)255; }

extern "C" void kernel_launch(void* const* d_in, const int* in_sizes, int n_in,
                              void* d_out, int out_size, void* d_ws, size_t ws_size,
                              hipStream_t stream) {
    const float* x      = (const float*)d_in[0];
    const int*   ei     = (const int*)d_in[1];
    const int*   et     = (const int*)d_in[2];
    const int*   batch  = (const int*)d_in[3];
    const float* w_in   = (const float*)d_in[4];
    const float* b_in   = (const float*)d_in[5];
    const float* rel_w  = (const float*)d_in[6];
    const float* root_w = (const float*)d_in[7];
    const float* conv_b = (const float*)d_in[8];
    const float* bn_g   = (const float*)d_in[9];
    const float* bn_b   = (const float*)d_in[10];
    const float* w_out  = (const float*)d_in[11];
    const float* b_out  = (const float*)d_in[12];
    float* out = (float*)d_out;

    char* ws = (char*)d_ws;
    size_t off = 0;
    u16*   h_bf  = (u16*)(ws + off);  off += align256((size_t)N_NODES * H_DIM * 2);
    float* outb  = (float*)(ws + off); off += align256((size_t)N_NODES * H_DIM * 4);
    u16*   x_bf  = (u16*)(ws + off);  off += align256((size_t)N_NODES * F_IN * 2);
    int*   cnt   = (int*)(ws + off);  off += align256((size_t)N_NODES * R_REL * 4);
    int*   e_src = (int*)(ws + off);  off += align256((size_t)E_EDGES * 4);
    int*   e_q   = (int*)(ws + off);  off += align256((size_t)E_EDGES * 4);
    float* e_norm = (float*)(ws + off); off += align256((size_t)E_EDGES * 4);
    int*   dst_cnt = (int*)(ws + off); off += align256((size_t)N_NODES * 4);
    int*   dst_off = (int*)(ws + off); off += align256((size_t)(N_NODES + 1) * 4);
    int*   dst_cur = (int*)(ws + off); off += align256((size_t)N_NODES * 4);
    u16*   wp_in   = (u16*)(ws + off); off += align256((size_t)F_IN * H_DIM * 2);
    u16*   wp_root = (u16*)(ws + off); off += align256((size_t)L_LAYERS * H_DIM * H_DIM * 2);
    u16*   wp_rel  = (u16*)(ws + off); off += align256((size_t)L_LAYERS * R_REL * H_DIM * H_DIM * 2);
    int*   type_count = (int*)(ws + off); off += 256;
    int*   type_off   = (int*)(ws + off); off += 256;
    int*   cursor     = (int*)(ws + off); off += 256;
    int*   scan_part  = (int*)(ws + off); off += 1024;
    float* bn_sums    = (float*)(ws + off); off += align256(2 * H_DIM * 4);
    float* pool       = (float*)(ws + off); off += align256((size_t)G_GRAPHS * H_DIM * 4);
    float* pcnt       = (float*)(ws + off); off += 256;
    u16*   m          = (u16*)(ws + off); off += align256((size_t)E_EDGES * H_DIM * 2);
    const int fast = (ws_size >= off) ? 1 : 0;   // m (last) only used in fast mode

    // ---- preprocessing ----
    hipMemsetAsync(cnt, 0, (size_t)N_NODES * R_REL * 4, stream);
    hipMemsetAsync(dst_cnt, 0, (size_t)N_NODES * 4, stream);
    hipMemsetAsync(type_count, 0, 256, stream);
    count_kernel<<<1024, 256, 0, stream>>>(ei, et, cnt, dst_cnt, type_count);
    scanR_kernel<<<1, 64, 0, stream>>>(type_count, type_off, cursor);
    if (fast) {
        hipMemsetAsync(dst_cur, 0, (size_t)N_NODES * 4, stream);
        const int NB = (N_NODES + 1023) / 1024;   // 98
        scan1_kernel<<<NB, 256, 0, stream>>>(dst_cnt, dst_off, scan_part);
        scan2_kernel<<<1, 128, 0, stream>>>(scan_part, NB);
        scan3_kernel<<<256, 256, 0, stream>>>(dst_off, scan_part);
    }
    bucket_kernel<<<(E_EDGES + 1023) / 1024, 256, 0, stream>>>(
        ei, et, cnt, dst_off, dst_cur, cursor, e_src, e_q, e_norm, fast);

    // ---- convert inputs / pack weights to bf16 ----
    cvt_bf16_kernel<<<2048, 256, 0, stream>>>(x, x_bf, N_NODES * F_IN / 4);
    pack_w<F_IN><<<1, 256, 0, stream>>>(w_in, wp_in);
    pack_w<H_DIM><<<L_LAYERS, 256, 0, stream>>>(root_w, wp_root);
    pack_w<H_DIM><<<L_LAYERS * R_REL, 256, 0, stream>>>(rel_w, wp_rel);

    // ---- input MLP: h = relu(x @ w_in + b_in)  -> bf16 ----
    mfma_gemm<F_IN, false, false, true, true, true, false><<<dim3(256, 1), 256, 0, stream>>>(
        x_bf, wp_in, b_in, h_bf, N_NODES, nullptr, nullptr, nullptr, nullptr);

    // ---- RGCN layers ----
    for (int l = 0; l < L_LAYERS; ++l) {
        // root/self transform + bias -> fp32 outb (dense)
        mfma_gemm<H_DIM, false, false, false, true, false, false><<<dim3(256, 1), 256, 0, stream>>>(
            h_bf, wp_root + (size_t)l * H_DIM * H_DIM, conv_b + (size_t)l * H_DIM, outb,
            N_NODES, nullptr, nullptr, nullptr, nullptr);
        if (fast) {
            // per-relation message GEMM -> m[q] (dst-sorted, norm applied, bf16)
            mfma_gemm<H_DIM, true, true, false, false, true, false><<<dim3(64, R_REL), 256, 0, stream>>>(
                h_bf, wp_rel + (size_t)l * R_REL * H_DIM * H_DIM, nullptr, m,
                0, type_off, e_src, e_q, e_norm);
            seg_reduce<<<(N_NODES + 63) / 64, 256, 0, stream>>>(m, dst_off, outb);
        } else {
            // fallback: atomic scatter straight into outb
            mfma_gemm<H_DIM, true, false, false, false, false, true><<<dim3(64, R_REL), 256, 0, stream>>>(
                h_bf, wp_rel + (size_t)l * R_REL * H_DIM * H_DIM, nullptr, outb,
                0, type_off, e_src, e_q, e_norm);
        }
        hipMemsetAsync(bn_sums, 0, 2 * H_DIM * 4, stream);
        bn_reduce<<<512, 256, 0, stream>>>(outb, bn_sums);
        bn_apply<<<2048, 256, 0, stream>>>(outb, bn_sums,
                                           bn_g + (size_t)l * H_DIM,
                                           bn_b + (size_t)l * H_DIM, h_bf);
    }

    // ---- global mean pool + classifier ----
    hipMemsetAsync(pool, 0, (size_t)G_GRAPHS * H_DIM * 4, stream);
    hipMemsetAsync(pcnt, 0, 256, stream);
    pool_kernel<<<512, 256, 0, stream>>>(h_bf, batch, pool, pcnt);
    logits_kernel<<<G_GRAPHS, 128, 0, stream>>>(pool, pcnt, w_out, b_out, out);
}

// Round 3
// 1993.221 us; speedup vs baseline: 3.1421x; 1.0129x over previous
//
#include <hip/hip_runtime.h>

#define N_NODES 100000
#define E_EDGES 1600000
#define F_IN    64
#define H_DIM   128
#define R_REL   20
#define G_GRAPHS 64
#define C_CLASSES 10
#define L_LAYERS 2
#define BN_EPS  1e-5f
#define RN      (R_REL * N_NODES)   // 2,000,000 (rel,dst) bins

typedef unsigned short u16;
typedef unsigned int   u32;
typedef __attribute__((ext_vector_type(8))) short short8;
typedef __attribute__((ext_vector_type(4))) float f32x4;

static __device__ __forceinline__ float bf2f(u16 u) {
    u32 b = ((u32)u) << 16;
    return __builtin_bit_cast(float, b);
}
static __device__ __forceinline__ u16 f2bf(float f) {
    u32 x = __builtin_bit_cast(u32, f);
    u32 r = x + 0x7fff + ((x >> 16) & 1);   // RNE; inputs finite
    return (u16)(r >> 16);
}

// ============================================================
// Edge preprocessing: histogram over (rel,dst), 3-level scan, counting sort
// ============================================================

// hist[t*N + d] += 1
__global__ void count_kernel(const int* __restrict__ ei, const int* __restrict__ et,
                             int* __restrict__ hist) {
    for (int e = blockIdx.x * blockDim.x + threadIdx.x; e < E_EDGES;
         e += gridDim.x * blockDim.x) {
        int t = et[e];
        int d = ei[E_EDGES + e];
        atomicAdd(&hist[t * N_NODES + d], 1);
    }
}

// exclusive scan, 1024 items / block
__global__ void scan1_kernel(const int* __restrict__ in, int* __restrict__ out,
                             int* __restrict__ part, int n) {
    __shared__ int s[256];
    int t = threadIdx.x;
    int base = blockIdx.x * 1024;
    int v[4]; int sum = 0;
#pragma unroll
    for (int j = 0; j < 4; ++j) {
        int i = base + t * 4 + j;
        v[j] = (i < n) ? in[i] : 0;
        sum += v[j];
    }
    s[t] = sum;
    __syncthreads();
    for (int off = 1; off < 256; off <<= 1) {
        int x = (t >= off) ? s[t - off] : 0;
        __syncthreads();
        s[t] += x;
        __syncthreads();
    }
    if (t == 255) part[blockIdx.x] = s[255];
    int run = s[t] - sum;
#pragma unroll
    for (int j = 0; j < 4; ++j) {
        int i = base + t * 4 + j;
        if (i < n) out[i] = run;
        run += v[j];
    }
}

// exclusive scan of up to 2048 partials in one block (8/thread)
__global__ void scan2_kernel(int* __restrict__ part, int nb) {
    __shared__ int s[256];
    int t = threadIdx.x;
    int loc[8]; int sum = 0;
#pragma unroll
    for (int j = 0; j < 8; ++j) {
        int i = t * 8 + j;
        loc[j] = (i < nb) ? part[i] : 0;
        sum += loc[j];
    }
    s[t] = sum;
    __syncthreads();
    for (int off = 1; off < 256; off <<= 1) {
        int x = (t >= off) ? s[t - off] : 0;
        __syncthreads();
        s[t] += x;
        __syncthreads();
    }
    int run = s[t] - sum;
#pragma unroll
    for (int j = 0; j < 8; ++j) {
        int i = t * 8 + j;
        if (i < nb) part[i] = run;
        run += loc[j];
    }
}

// add block bases; also mirror result into cur2 (atomic cursors for the sort)
__global__ void scan3_kernel(int* __restrict__ out, int* __restrict__ cur2,
                             const int* __restrict__ part, int n) {
    for (int i = blockIdx.x * blockDim.x + threadIdx.x; i < n;
         i += gridDim.x * blockDim.x) {
        int v = out[i] + part[i >> 10];
        out[i] = v;
        cur2[i] = v;
    }
}

// sentinel + per-relation bucket bounds
__global__ void finalize_kernel(int* __restrict__ off2, int* __restrict__ type_off) {
    int t = threadIdx.x;
    if (t == 0) off2[RN] = E_EDGES;
    if (t <= R_REL)
        type_off[t] = (t == R_REL) ? E_EDGES : off2[t * N_NODES];
}

// counting sort into (rel,dst) order; per-edge src idx + mean norm
__global__ void bucket_kernel(const int* __restrict__ ei, const int* __restrict__ et,
                              const int* __restrict__ off2, int* __restrict__ cur2,
                              int* __restrict__ esrc, int* __restrict__ eq,
                              float* __restrict__ enorm, int fast) {
    for (int e = blockIdx.x * blockDim.x + threadIdx.x; e < E_EDGES;
         e += gridDim.x * blockDim.x) {
        int t = et[e];
        int s = ei[e];
        int d = ei[E_EDGES + e];
        int i = t * N_NODES + d;
        int pos = atomicAdd(&cur2[i], 1);
        esrc[pos]  = s;
        enorm[pos] = 1.0f / (float)(off2[i + 1] - off2[i]);
        if (!fast) eq[pos] = d;
    }
}

// ============================================================
// Weight pack: fp32 [K,128] -> bf16 MFMA-frag order (verified R2)
// ============================================================
template<int K>
__global__ void pack_w(const float* __restrict__ W, u16* __restrict__ Wp) {
    const float* w = W + (size_t)blockIdx.x * K * H_DIM;
    u16* p = Wp + (size_t)blockIdx.x * K * H_DIM;
    for (int o = threadIdx.x; o < K * H_DIM; o += blockDim.x) {
        int j  = o & 7;
        int l  = (o >> 3) & 63;
        int ct = (o >> 9) & 7;
        int kt = o >> 12;
        int k  = kt * 32 + (l >> 4) * 8 + j;
        int n  = ct * 16 + (l & 15);
        p[o] = f2bf(w[(size_t)k * H_DIM + n]);
    }
}

__global__ void cvt_bf16_kernel(const float* __restrict__ in, u16* __restrict__ out, int n4) {
    for (int i = blockIdx.x * blockDim.x + threadIdx.x; i < n4;
         i += gridDim.x * blockDim.x) {
        float4 v = ((const float4*)in)[i];
        ushort4 o;
        o.x = f2bf(v.x); o.y = f2bf(v.y); o.z = f2bf(v.z); o.w = f2bf(v.w);
        ((ushort4*)out)[i] = o;
    }
}

// ============================================================
// Dense MFMA GEMM (input MLP, root transform) — proven R2 structure
// ============================================================
template<int K, bool RELU, bool HASBIAS, bool OUTBF16>
__global__ __launch_bounds__(256)
void mfma_dense(const u16* __restrict__ A, const u16* __restrict__ Wp,
                const float* __restrict__ bias, void* __restrict__ OutV, int M) {
    constexpr int CH = K / 8;
    __shared__ u16 Ws[K * H_DIM];
    __shared__ u16 As[64 * H_DIM];

    for (int o = threadIdx.x; o < K * H_DIM / 8; o += 256)
        ((short8*)Ws)[o] = ((const short8*)Wp)[o];

    const int lane = threadIdx.x & 63;
    const int wave = threadIdx.x >> 6;
    const int l15  = lane & 15;
    const int kgrp = lane >> 4;
    const int arow = wave * 16 + l15;

    for (int tb = blockIdx.x * 64; tb < M; tb += gridDim.x * 64) {
        __syncthreads();
        for (int o = threadIdx.x; o < 64 * CH; o += 256) {
            int row = o / CH, cc = o % CH;
            int grow = tb + row;
            short8 v = {0,0,0,0,0,0,0,0};
            if (grow < M) v = *(const short8*)&A[(size_t)grow * K + cc * 8];
            *(short8*)&As[row * K + ((cc ^ (row & 7)) * 8)] = v;
        }
        __syncthreads();

        f32x4 acc[8];
#pragma unroll
        for (int i = 0; i < 8; ++i) {
            acc[i][0] = 0.f; acc[i][1] = 0.f; acc[i][2] = 0.f; acc[i][3] = 0.f;
        }
#pragma unroll
        for (int kt = 0; kt < K / 32; ++kt) {
            short8 af = *(const short8*)&As[arow * K + (((kt * 4 + kgrp) ^ (arow & 7)) * 8)];
#pragma unroll
            for (int ct = 0; ct < 8; ++ct) {
                short8 bf = *(const short8*)&Ws[(((kt * 8 + ct) * 64) + lane) * 8];
                acc[ct] = __builtin_amdgcn_mfma_f32_16x16x32_bf16(af, bf, acc[ct], 0, 0, 0);
            }
        }

        if (OUTBF16) {
            __syncthreads();
#pragma unroll
            for (int ct = 0; ct < 8; ++ct) {
#pragma unroll
                for (int r = 0; r < 4; ++r) {
                    int row = wave * 16 + kgrp * 4 + r;
                    int col = ct * 16 + l15;
                    float v = acc[ct][r];
                    if (HASBIAS) v += bias[col];
                    if (RELU)    v = fmaxf(v, 0.f);
                    As[row * H_DIM + ((((col >> 3) ^ (row & 7)) << 3) | (col & 7))] = f2bf(v);
                }
            }
            __syncthreads();
            u16* Out = (u16*)OutV;
            for (int o = threadIdx.x; o < 64 * 16; o += 256) {
                int row = o >> 4, cc = o & 15;
                int grow = tb + row;
                if (grow < M)
                    *(short8*)&Out[(size_t)grow * H_DIM + cc * 8] =
                        *(const short8*)&As[row * H_DIM + ((cc ^ (row & 7)) << 3)];
            }
        } else {
            float* Out = (float*)OutV;
#pragma unroll
            for (int ct = 0; ct < 8; ++ct) {
#pragma unroll
                for (int r = 0; r < 4; ++r) {
                    int grow = tb + wave * 16 + kgrp * 4 + r;
                    if (grow < M) {
                        float v = acc[ct][r];
                        if (HASBIAS) v += bias[ct * 16 + l15];
                        if (RELU)    v = fmaxf(v, 0.f);
                        Out[(size_t)grow * H_DIM + ct * 16 + l15] = v;
                    }
                }
            }
        }
    }
}

// ============================================================
// Edge GEMM: barrier-free, per-wave. Wave owns a fixed 64-col half;
// W in VGPRs; A-frags gathered directly from global; linear bf16 store
// (edges sorted by (rel,dst) -> m rows already dst-grouped per relation).
// ============================================================
template<bool ATOMIC>
__global__ __launch_bounds__(256, 4)
void edge_gemm(const u16* __restrict__ A, const u16* __restrict__ Wp,
               void* __restrict__ OutV, const int* __restrict__ boundsp,
               const int* __restrict__ gidx, const int* __restrict__ eq,
               const float* __restrict__ rownorm) {
    __shared__ u16 RB[4][16 * 64];   // per-wave repack buffer (2 KB each)

    const int lane = threadIdx.x & 63;
    const int wv   = threadIdx.x >> 6;
    const int l15  = lane & 15;
    const int kgrp = lane >> 4;

    const int rel = blockIdx.y;
    const int mb = boundsp[rel], me = boundsp[rel + 1];
    const u16* W = Wp + (size_t)rel * H_DIM * H_DIM;

    const int wid = blockIdx.x * 4 + wv;
    const int nw  = gridDim.x * 4;
    const int hc  = wid & 1;                       // column half (fixed per wave)
    const int ntiles = (me - mb + 15) >> 4;

    // load this wave's W fragments (4 kt x 4 ct, 64 VGPRs)
    short8 wf[4][4];
#pragma unroll
    for (int kt = 0; kt < 4; ++kt)
#pragma unroll
        for (int ct = 0; ct < 4; ++ct)
            wf[kt][ct] = *(const short8*)&W[(((kt * 8 + hc * 4 + ct) * 64) + lane) * 8];

    u16* lds = RB[wv];

    for (int tile = wid >> 1; tile < ntiles; tile += nw >> 1) {
        const int tb = mb + tile * 16;
        const int rowg = tb + l15;
        const int g = (rowg < me) ? gidx[rowg] : 0;

        short8 af[4];
#pragma unroll
        for (int kt = 0; kt < 4; ++kt)
            af[kt] = *(const short8*)&A[(size_t)g * H_DIM + kt * 32 + kgrp * 8];

        f32x4 acc[4];
#pragma unroll
        for (int ct = 0; ct < 4; ++ct) {
            acc[ct][0] = 0.f; acc[ct][1] = 0.f; acc[ct][2] = 0.f; acc[ct][3] = 0.f;
        }
#pragma unroll
        for (int kt = 0; kt < 4; ++kt)
#pragma unroll
            for (int ct = 0; ct < 4; ++ct)
                acc[ct] = __builtin_amdgcn_mfma_f32_16x16x32_bf16(af[kt], wf[kt][ct], acc[ct], 0, 0, 0);

        if (ATOMIC) {
            float* Out = (float*)OutV;
#pragma unroll
            for (int rr = 0; rr < 4; ++rr) {
                int rg = tb + kgrp * 4 + rr;
                if (rg < me) {
                    int dd = eq[rg];
                    float sc = rownorm[rg];
#pragma unroll
                    for (int ct = 0; ct < 4; ++ct)
                        atomicAdd(&Out[(size_t)dd * H_DIM + hc * 64 + ct * 16 + l15],
                                  acc[ct][rr] * sc);
                }
            }
        } else {
            float rn[4];
#pragma unroll
            for (int rr = 0; rr < 4; ++rr) {
                int rg = tb + kgrp * 4 + rr;
                rn[rr] = (rg < me) ? rownorm[rg] : 0.f;
            }
            // repack D-frags -> row-major via wave-private LDS (XOR-by-kgrp swizzle)
#pragma unroll
            for (int ct = 0; ct < 4; ++ct) {
#pragma unroll
                for (int rr = 0; rr < 4; ++rr) {
                    int row  = kgrp * 4 + rr;
                    int colb = (ct * 16 + l15) * 2;             // byte col in 128B half-row
                    *(u16*)((char*)lds + row * 128 + (colb ^ (kgrp << 5))) =
                        f2bf(acc[ct][rr] * rn[rr]);
                }
            }
            u16* Out = (u16*)OutV;
#pragma unroll
            for (int rep = 0; rep < 2; ++rep) {
                int o   = lane + rep * 64;
                int row = o >> 3;                                // 0..15
                int ch  = o & 7;                                 // 16B chunk
                short8 v = *(const short8*)((char*)lds + row * 128 +
                                            ((ch * 16) ^ ((row >> 2) << 5)));
                int rg = tb + row;
                if (rg < me)
                    *(short8*)&Out[(size_t)rg * H_DIM + hc * 64 + ch * 8] = v;
            }
        }
    }
}

// ============================================================
// Segment sum: outb[d] += sum over r of m rows in [off2[r*N+d], off2[r*N+d+1])
// block = 64 dsts; offsets staged in LDS; streaming m reads; no atomics
// ============================================================
__global__ void seg_reduce(const u16* __restrict__ m, const int* __restrict__ off2,
                           float* __restrict__ outb) {
    __shared__ int offs[R_REL * 65];
    const int d0 = blockIdx.x * 64;
    for (int i = threadIdx.x; i < R_REL * 65; i += 256) {
        int r = i / 65, j = i % 65;
        int idx = r * N_NODES + d0 + j;
        offs[i] = off2[min(idx, RN)];
    }
    __syncthreads();

    const int wv = threadIdx.x >> 6, lane = threadIdx.x & 63;
    const u32* m2 = (const u32*)m;
    for (int di = wv; di < 64; di += 4) {
        int d = d0 + di;
        if (d >= N_NODES) break;
        float a0 = 0.f, a1 = 0.f;
#pragma unroll 4
        for (int r = 0; r < R_REL; ++r) {
            int s = offs[r * 65 + di];
            int e = offs[r * 65 + di + 1];
            for (int i = s; i < e; ++i) {
                u32 v = m2[(size_t)i * 64 + lane];
                a0 += bf2f((u16)(v & 0xffff));
                a1 += bf2f((u16)(v >> 16));
            }
        }
        float* op = &outb[(size_t)d * H_DIM + lane * 2];
        op[0] += a0;
        op[1] += a1;
    }
}

// ============================================================
// BatchNorm + ReLU -> bf16 h
// ============================================================
__global__ void bn_reduce(const float* __restrict__ X, float* __restrict__ sums) {
    int col  = threadIdx.x & 127;
    int half = threadIdx.x >> 7;
    float s = 0.f, ss = 0.f;
    for (int row = blockIdx.x * 2 + half; row < N_NODES; row += gridDim.x * 2) {
        float v = X[(size_t)row * H_DIM + col];
        s += v; ss += v * v;
    }
    atomicAdd(&sums[col], s);
    atomicAdd(&sums[H_DIM + col], ss);
}

__global__ void bn_apply(const float* __restrict__ X, const float* __restrict__ sums,
                         const float* __restrict__ gg, const float* __restrict__ bb,
                         u16* __restrict__ Hout) {
    __shared__ float sc[H_DIM], sh[H_DIM];
    if (threadIdx.x < H_DIM) {
        float mean = sums[threadIdx.x] * (1.0f / N_NODES);
        float var  = sums[H_DIM + threadIdx.x] * (1.0f / N_NODES) - mean * mean;
        float inv  = rsqrtf(var + BN_EPS) * gg[threadIdx.x];
        sc[threadIdx.x] = inv;
        sh[threadIdx.x] = bb[threadIdx.x] - mean * inv;
    }
    __syncthreads();
    int total = N_NODES * (H_DIM / 4);
    for (int idx = blockIdx.x * 256 + threadIdx.x; idx < total; idx += gridDim.x * 256) {
        float4 v = ((const float4*)X)[idx];
        int c = (idx & 31) << 2;
        ushort4 o;
        o.x = f2bf(fmaxf(v.x * sc[c + 0] + sh[c + 0], 0.f));
        o.y = f2bf(fmaxf(v.y * sc[c + 1] + sh[c + 1], 0.f));
        o.z = f2bf(fmaxf(v.z * sc[c + 2] + sh[c + 2], 0.f));
        o.w = f2bf(fmaxf(v.w * sc[c + 3] + sh[c + 3], 0.f));
        ((ushort4*)Hout)[idx] = o;
    }
}

// ============================================================
// Pool + classifier
// ============================================================
__global__ void pool_kernel(const u16* __restrict__ Hf, const int* __restrict__ batch,
                            float* __restrict__ pool, float* __restrict__ pcnt) {
    int col  = threadIdx.x & 127;
    int half = threadIdx.x >> 7;
    int chunk = (N_NODES + gridDim.x - 1) / gridDim.x;
    int start = blockIdx.x * chunk;
    int end   = min(N_NODES, start + chunk);
    int curg = -1;
    float acc = 0.f, c = 0.f;
    for (int row = start + half; row < end; row += 2) {
        int g = batch[row];
        if (g != curg) {
            if (curg >= 0) {
                atomicAdd(&pool[curg * H_DIM + col], acc);
                if (col == 0) atomicAdd(&pcnt[curg], c);
            }
            curg = g; acc = 0.f; c = 0.f;
        }
        acc += bf2f(Hf[(size_t)row * H_DIM + col]);
        c += 1.f;
    }
    if (curg >= 0) {
        atomicAdd(&pool[curg * H_DIM + col], acc);
        if (col == 0) atomicAdd(&pcnt[curg], c);
    }
}

__global__ void logits_kernel(const float* __restrict__ pool, const float* __restrict__ pcnt,
                              const float* __restrict__ w_out, const float* __restrict__ b_out,
                              float* __restrict__ out) {
    int g = blockIdx.x;
    __shared__ float p[H_DIM];
    float cnt = fmaxf(pcnt[g], 1.0f);
    p[threadIdx.x] = pool[g * H_DIM + threadIdx.x] / cnt;
    __syncthreads();
    if (threadIdx.x < C_CLASSES) {
        float acc = b_out[threadIdx.x];
        for (int k = 0; k < H_DIM; ++k)
            acc += p[k] * w_out[k * C_CLASSES + threadIdx.x];
        out[g * C_CLASSES + threadIdx.x] = 1.0f / (1.0f + expf(-acc));
    }
}

// ============================================================
// Host launch
// ============================================================
static inline size_t align256(size_t x) { return (x + 255) & ~(size_t)255; }

extern "C" void kernel_launch(void* const* d_in, const int* in_sizes, int n_in,
                              void* d_out, int out_size, void* d_ws, size_t ws_size,
                              hipStream_t stream) {
    const float* x      = (const float*)d_in[0];
    const int*   ei     = (const int*)d_in[1];
    const int*   et     = (const int*)d_in[2];
    const int*   batch  = (const int*)d_in[3];
    const float* w_in   = (const float*)d_in[4];
    const float* b_in   = (const float*)d_in[5];
    const float* rel_w  = (const float*)d_in[6];
    const float* root_w = (const float*)d_in[7];
    const float* conv_b = (const float*)d_in[8];
    const float* bn_g   = (const float*)d_in[9];
    const float* bn_b   = (const float*)d_in[10];
    const float* w_out  = (const float*)d_in[11];
    const float* b_out  = (const float*)d_in[12];
    float* out = (float*)d_out;

    char* ws = (char*)d_ws;
    size_t off = 0;
    u16*   h_bf  = (u16*)(ws + off);  off += align256((size_t)N_NODES * H_DIM * 2);
    float* outb  = (float*)(ws + off); off += align256((size_t)N_NODES * H_DIM * 4);
    u16*   x_bf  = (u16*)(ws + off);  off += align256((size_t)N_NODES * F_IN * 2);
    int*   off2  = (int*)(ws + off);  off += align256((size_t)(RN + 1) * 4 + 256);
    int*   cur2  = (int*)(ws + off);  off += align256((size_t)RN * 4);
    int*   e_src = (int*)(ws + off);  off += align256((size_t)E_EDGES * 4 + 256);
    int*   e_q   = (int*)(ws + off);  off += align256((size_t)E_EDGES * 4);
    float* e_norm = (float*)(ws + off); off += align256((size_t)E_EDGES * 4 + 256);
    u16*   wp_in   = (u16*)(ws + off); off += align256((size_t)F_IN * H_DIM * 2);
    u16*   wp_root = (u16*)(ws + off); off += align256((size_t)L_LAYERS * H_DIM * H_DIM * 2);
    u16*   wp_rel  = (u16*)(ws + off); off += align256((size_t)L_LAYERS * R_REL * H_DIM * H_DIM * 2);
    int*   type_off   = (int*)(ws + off); off += 256;
    int*   scan_part  = (int*)(ws + off); off += align256(2048 * 4);
    float* bn_sums    = (float*)(ws + off); off += align256(2 * H_DIM * 4);
    float* pool       = (float*)(ws + off); off += align256((size_t)G_GRAPHS * H_DIM * 4);
    float* pcnt       = (float*)(ws + off); off += 256;
    u16*   m          = (u16*)(ws + off); off += align256((size_t)E_EDGES * H_DIM * 2);
    const int fast = (ws_size >= off) ? 1 : 0;   // m (last) only used in fast mode

    // ---- preprocessing: histogram -> scan -> (rel,dst) counting sort ----
    hipMemsetAsync(cur2, 0, (size_t)RN * 4, stream);    // cur2 doubles as histogram
    count_kernel<<<1024, 256, 0, stream>>>(ei, et, cur2);
    const int NB = (RN + 1023) / 1024;                   // 1954
    scan1_kernel<<<NB, 256, 0, stream>>>(cur2, off2, scan_part, RN);
    scan2_kernel<<<1, 256, 0, stream>>>(scan_part, NB);
    scan3_kernel<<<2048, 256, 0, stream>>>(off2, cur2, scan_part, RN);
    finalize_kernel<<<1, 64, 0, stream>>>(off2, type_off);
    bucket_kernel<<<2048, 256, 0, stream>>>(ei, et, off2, cur2, e_src, e_q, e_norm, fast);

    // ---- convert inputs / pack weights to bf16 ----
    cvt_bf16_kernel<<<2048, 256, 0, stream>>>(x, x_bf, N_NODES * F_IN / 4);
    pack_w<F_IN><<<1, 256, 0, stream>>>(w_in, wp_in);
    pack_w<H_DIM><<<L_LAYERS, 256, 0, stream>>>(root_w, wp_root);
    pack_w<H_DIM><<<L_LAYERS * R_REL, 256, 0, stream>>>(rel_w, wp_rel);

    // ---- input MLP: h = relu(x @ w_in + b_in) -> bf16 ----
    mfma_dense<F_IN, true, true, true><<<dim3(256), 256, 0, stream>>>(
        x_bf, wp_in, b_in, h_bf, N_NODES);

    // ---- RGCN layers ----
    for (int l = 0; l < L_LAYERS; ++l) {
        // root/self transform + bias -> fp32 outb
        mfma_dense<H_DIM, false, true, false><<<dim3(256), 256, 0, stream>>>(
            h_bf, wp_root + (size_t)l * H_DIM * H_DIM, conv_b + (size_t)l * H_DIM,
            outb, N_NODES);
        if (fast) {
            // per-relation message GEMM -> m (linear store, (rel,dst)-sorted)
            edge_gemm<false><<<dim3(52, R_REL), 256, 0, stream>>>(
                h_bf, wp_rel + (size_t)l * R_REL * H_DIM * H_DIM, m,
                type_off, e_src, e_q, e_norm);
            seg_reduce<<<(N_NODES + 63) / 64, 256, 0, stream>>>(m, off2, outb);
        } else {
            edge_gemm<true><<<dim3(52, R_REL), 256, 0, stream>>>(
                h_bf, wp_rel + (size_t)l * R_REL * H_DIM * H_DIM, outb,
                type_off, e_src, e_q, e_norm);
        }
        hipMemsetAsync(bn_sums, 0, 2 * H_DIM * 4, stream);
        bn_reduce<<<512, 256, 0, stream>>>(outb, bn_sums);
        bn_apply<<<2048, 256, 0, stream>>>(outb, bn_sums,
                                           bn_g + (size_t)l * H_DIM,
                                           bn_b + (size_t)l * H_DIM, h_bf);
    }

    // ---- global mean pool + classifier ----
    hipMemsetAsync(pool, 0, (size_t)G_GRAPHS * H_DIM * 4, stream);
    hipMemsetAsync(pcnt, 0, 256, stream);
    pool_kernel<<<512, 256, 0, stream>>>(h_bf, batch, pool, pcnt);
    logits_kernel<<<G_GRAPHS, 128, 0, stream>>>(pool, pcnt, w_out, b_out, out);
}

// Round 4
// 1423.762 us; speedup vs baseline: 4.3988x; 1.4000x over previous
//
#include <hip/hip_runtime.h>

#define N_NODES 100000
#define E_EDGES 1600000
#define F_IN    64
#define H_DIM   128
#define R_REL   20
#define G_GRAPHS 64
#define C_CLASSES 10
#define L_LAYERS 2
#define BN_EPS  1e-5f
#define RN      (R_REL * N_NODES)   // 2,000,000 (rel,dst) bins

typedef unsigned short u16;
typedef unsigned int   u32;
typedef __attribute__((ext_vector_type(8))) short short8;
typedef __attribute__((ext_vector_type(4))) float f32x4;

static __device__ __forceinline__ float bf2f(u16 u) {
    u32 b = ((u32)u) << 16;
    return __builtin_bit_cast(float, b);
}
static __device__ __forceinline__ u16 f2bf(float f) {
    u32 x = __builtin_bit_cast(u32, f);
    u32 r = x + 0x7fff + ((x >> 16) & 1);   // RNE; inputs finite
    return (u16)(r >> 16);
}

// ============================================================
// Edge preprocessing: histogram over (rel,dst), 3-level scan, counting sort
// ============================================================

__global__ void count_kernel(const int* __restrict__ ei, const int* __restrict__ et,
                             int* __restrict__ hist) {
    for (int e = blockIdx.x * blockDim.x + threadIdx.x; e < E_EDGES;
         e += gridDim.x * blockDim.x) {
        int t = et[e];
        int d = ei[E_EDGES + e];
        atomicAdd(&hist[t * N_NODES + d], 1);
    }
}

// exclusive scan, 1024 items / block
__global__ void scan1_kernel(const int* __restrict__ in, int* __restrict__ out,
                             int* __restrict__ part, int n) {
    __shared__ int s[256];
    int t = threadIdx.x;
    int base = blockIdx.x * 1024;
    int v[4]; int sum = 0;
#pragma unroll
    for (int j = 0; j < 4; ++j) {
        int i = base + t * 4 + j;
        v[j] = (i < n) ? in[i] : 0;
        sum += v[j];
    }
    s[t] = sum;
    __syncthreads();
    for (int off = 1; off < 256; off <<= 1) {
        int x = (t >= off) ? s[t - off] : 0;
        __syncthreads();
        s[t] += x;
        __syncthreads();
    }
    if (t == 255) part[blockIdx.x] = s[255];
    int run = s[t] - sum;
#pragma unroll
    for (int j = 0; j < 4; ++j) {
        int i = base + t * 4 + j;
        if (i < n) out[i] = run;
        run += v[j];
    }
}

// exclusive scan of up to 2048 partials in one block (8/thread)
__global__ void scan2_kernel(int* __restrict__ part, int nb) {
    __shared__ int s[256];
    int t = threadIdx.x;
    int loc[8]; int sum = 0;
#pragma unroll
    for (int j = 0; j < 8; ++j) {
        int i = t * 8 + j;
        loc[j] = (i < nb) ? part[i] : 0;
        sum += loc[j];
    }
    s[t] = sum;
    __syncthreads();
    for (int off = 1; off < 256; off <<= 1) {
        int x = (t >= off) ? s[t - off] : 0;
        __syncthreads();
        s[t] += x;
        __syncthreads();
    }
    int run = s[t] - sum;
#pragma unroll
    for (int j = 0; j < 8; ++j) {
        int i = t * 8 + j;
        if (i < nb) part[i] = run;
        run += loc[j];
    }
}

// add block bases; mirror into cur2 (atomic cursors for the sort)
__global__ void scan3_kernel(int* __restrict__ out, int* __restrict__ cur2,
                             const int* __restrict__ part, int n) {
    for (int i = blockIdx.x * blockDim.x + threadIdx.x; i < n;
         i += gridDim.x * blockDim.x) {
        int v = out[i] + part[i >> 10];
        out[i] = v;
        cur2[i] = v;
    }
}

__global__ void finalize_kernel(int* __restrict__ off2) {
    if (threadIdx.x == 0) off2[RN] = E_EDGES;
}

// counting sort into (rel,dst) order; only src index needed downstream
__global__ void bucket_kernel(const int* __restrict__ ei, const int* __restrict__ et,
                              int* __restrict__ cur2, int* __restrict__ esrc) {
    for (int e = blockIdx.x * blockDim.x + threadIdx.x; e < E_EDGES;
         e += gridDim.x * blockDim.x) {
        int t = et[e];
        int s = ei[e];
        int d = ei[E_EDGES + e];
        int pos = atomicAdd(&cur2[t * N_NODES + d], 1);
        esrc[pos] = s;
    }
}

// ============================================================
// Weight pack: fp32 [K,128] -> bf16 MFMA-frag order (verified R2/R3)
// ============================================================
template<int K>
__global__ void pack_w(const float* __restrict__ W, u16* __restrict__ Wp) {
    const float* w = W + (size_t)blockIdx.x * K * H_DIM;
    u16* p = Wp + (size_t)blockIdx.x * K * H_DIM;
    for (int o = threadIdx.x; o < K * H_DIM; o += blockDim.x) {
        int j  = o & 7;
        int l  = (o >> 3) & 63;
        int ct = (o >> 9) & 7;
        int kt = o >> 12;
        int k  = kt * 32 + (l >> 4) * 8 + j;
        int n  = ct * 16 + (l & 15);
        p[o] = f2bf(w[(size_t)k * H_DIM + n]);
    }
}

__global__ void cvt_bf16_kernel(const float* __restrict__ in, u16* __restrict__ out, int n4) {
    for (int i = blockIdx.x * blockDim.x + threadIdx.x; i < n4;
         i += gridDim.x * blockDim.x) {
        float4 v = ((const float4*)in)[i];
        ushort4 o;
        o.x = f2bf(v.x); o.y = f2bf(v.y); o.z = f2bf(v.z); o.w = f2bf(v.w);
        ((ushort4*)out)[i] = o;
    }
}

// ============================================================
// Dense MFMA GEMM (input MLP, root transform) — proven R2/R3 structure
// ============================================================
template<int K, bool RELU, bool HASBIAS, bool OUTBF16>
__global__ __launch_bounds__(256)
void mfma_dense(const u16* __restrict__ A, const u16* __restrict__ Wp,
                const float* __restrict__ bias, void* __restrict__ OutV, int M) {
    constexpr int CH = K / 8;
    __shared__ u16 Ws[K * H_DIM];
    __shared__ u16 As[64 * H_DIM];

    for (int o = threadIdx.x; o < K * H_DIM / 8; o += 256)
        ((short8*)Ws)[o] = ((const short8*)Wp)[o];

    const int lane = threadIdx.x & 63;
    const int wave = threadIdx.x >> 6;
    const int l15  = lane & 15;
    const int kgrp = lane >> 4;
    const int arow = wave * 16 + l15;

    for (int tb = blockIdx.x * 64; tb < M; tb += gridDim.x * 64) {
        __syncthreads();
        for (int o = threadIdx.x; o < 64 * CH; o += 256) {
            int row = o / CH, cc = o % CH;
            int grow = tb + row;
            short8 v = {0,0,0,0,0,0,0,0};
            if (grow < M) v = *(const short8*)&A[(size_t)grow * K + cc * 8];
            *(short8*)&As[row * K + ((cc ^ (row & 7)) * 8)] = v;
        }
        __syncthreads();

        f32x4 acc[8];
#pragma unroll
        for (int i = 0; i < 8; ++i) {
            acc[i][0] = 0.f; acc[i][1] = 0.f; acc[i][2] = 0.f; acc[i][3] = 0.f;
        }
#pragma unroll
        for (int kt = 0; kt < K / 32; ++kt) {
            short8 af = *(const short8*)&As[arow * K + (((kt * 4 + kgrp) ^ (arow & 7)) * 8)];
#pragma unroll
            for (int ct = 0; ct < 8; ++ct) {
                short8 bf = *(const short8*)&Ws[(((kt * 8 + ct) * 64) + lane) * 8];
                acc[ct] = __builtin_amdgcn_mfma_f32_16x16x32_bf16(af, bf, acc[ct], 0, 0, 0);
            }
        }

        if (OUTBF16) {
            __syncthreads();
#pragma unroll
            for (int ct = 0; ct < 8; ++ct) {
#pragma unroll
                for (int r = 0; r < 4; ++r) {
                    int row = wave * 16 + kgrp * 4 + r;
                    int col = ct * 16 + l15;
                    float v = acc[ct][r];
                    if (HASBIAS) v += bias[col];
                    if (RELU)    v = fmaxf(v, 0.f);
                    As[row * H_DIM + ((((col >> 3) ^ (row & 7)) << 3) | (col & 7))] = f2bf(v);
                }
            }
            __syncthreads();
            u16* Out = (u16*)OutV;
            for (int o = threadIdx.x; o < 64 * 16; o += 256) {
                int row = o >> 4, cc = o & 15;
                int grow = tb + row;
                if (grow < M)
                    *(short8*)&Out[(size_t)grow * H_DIM + cc * 8] =
                        *(const short8*)&As[row * H_DIM + ((cc ^ (row & 7)) << 3)];
            }
        } else {
            float* Out = (float*)OutV;
#pragma unroll
            for (int ct = 0; ct < 8; ++ct) {
#pragma unroll
                for (int r = 0; r < 4; ++r) {
                    int grow = tb + wave * 16 + kgrp * 4 + r;
                    if (grow < M) {
                        float v = acc[ct][r];
                        if (HASBIAS) v += bias[ct * 16 + l15];
                        if (RELU)    v = fmaxf(v, 0.f);
                        Out[(size_t)grow * H_DIM + ct * 16 + l15] = v;
                    }
                }
            }
        }
    }
}

// ============================================================
// Fused RGCN conv: block owns 128 dst nodes; per relation:
//   aggregate mean(h[src]) into swizzled LDS A-tile (wave-private bins,
//   coalesced 256B row gathers, no atomics) -> MFMA vs LDS-staged W_r,
//   accumulator kept across all 20 relations -> one exclusive outb += epilogue.
// No per-edge messages materialized; everything L3-resident.
// ============================================================
__global__ __launch_bounds__(512, 4)
void rgcn_conv(const u16* __restrict__ h, const u16* __restrict__ Wl,
               const int* __restrict__ esrc, const int* __restrict__ off2,
               float* __restrict__ outb) {
    __shared__ int offs[R_REL][129];
    __shared__ u16 Ws[H_DIM * H_DIM];      // 32 KB, frag-packed W_r
    __shared__ u16 Abf[128 * H_DIM];       // 32 KB, swizzled A-tile

    const int d0 = blockIdx.x * 128;
    for (int i = threadIdx.x; i < R_REL * 129; i += 512) {
        int r = i / 129, j = i % 129;
        offs[r][j] = off2[r * N_NODES + min(d0 + j, N_NODES)];
    }

    const int lane = threadIdx.x & 63;
    const int wv   = threadIdx.x >> 6;     // 0..7
    const int l15  = lane & 15;
    const int kgrp = lane >> 4;
    const int arow = wv * 16 + l15;
    const u32* h2 = (const u32*)h;

    f32x4 acc[8];
#pragma unroll
    for (int i = 0; i < 8; ++i) {
        acc[i][0] = 0.f; acc[i][1] = 0.f; acc[i][2] = 0.f; acc[i][3] = 0.f;
    }

    for (int r = 0; r < R_REL; ++r) {
        __syncthreads();   // Ws free (prev rel readers done); offs ready (r=0)
        // stage frag-packed W_r
        for (int o = threadIdx.x; o < H_DIM * H_DIM / 8; o += 512)
            ((short8*)Ws)[o] = ((const short8*)(Wl + (size_t)r * H_DIM * H_DIM))[o];

        // aggregate this wave's 16 bins (rows are wave-private -> no races)
        for (int bi = 0; bi < 16; ++bi) {
            int bin = wv * 16 + bi;
            int s = offs[r][bin], e = offs[r][bin + 1];
            float f0 = 0.f, f1 = 0.f;
            int i = s;
            for (; i + 1 < e; i += 2) {
                int s0 = esrc[i], s1 = esrc[i + 1];
                u32 a = h2[(size_t)s0 * 64 + lane];
                u32 b = h2[(size_t)s1 * 64 + lane];
                f0 += bf2f((u16)(a & 0xffff)) + bf2f((u16)(b & 0xffff));
                f1 += bf2f((u16)(a >> 16)) + bf2f((u16)(b >> 16));
            }
            if (i < e) {
                u32 a = h2[(size_t)esrc[i] * 64 + lane];
                f0 += bf2f((u16)(a & 0xffff));
                f1 += bf2f((u16)(a >> 16));
            }
            float nm = 1.0f / (float)max(e - s, 1);
            u32 pack = (u32)f2bf(f0 * nm) | ((u32)f2bf(f1 * nm) << 16);
            // swizzled write: lane covers u16 cols 2l,2l+1; chunk = l>>2
            ((u32*)Abf)[bin * 64 + (((lane >> 2) ^ (bin & 7)) << 2) + (lane & 3)] = pack;
        }
        __syncthreads();   // Abf + Ws visible

        // MFMA: acc += A_r @ W_r  (accumulate across relations)
#pragma unroll
        for (int kt = 0; kt < 4; ++kt) {
            short8 af = *(const short8*)&Abf[arow * H_DIM + (((kt * 4 + kgrp) ^ (arow & 7)) * 8)];
#pragma unroll
            for (int ct = 0; ct < 8; ++ct) {
                short8 bf = *(const short8*)&Ws[(((kt * 8 + ct) * 64) + lane) * 8];
                acc[ct] = __builtin_amdgcn_mfma_f32_16x16x32_bf16(af, bf, acc[ct], 0, 0, 0);
            }
        }
    }

    // epilogue: exclusive read-modify-write into outb (pre-filled with root+bias)
#pragma unroll
    for (int ct = 0; ct < 8; ++ct) {
#pragma unroll
        for (int rr = 0; rr < 4; ++rr) {
            int grow = d0 + wv * 16 + kgrp * 4 + rr;
            if (grow < N_NODES) {
                float* p = &outb[(size_t)grow * H_DIM + ct * 16 + l15];
                *p += acc[ct][rr];
            }
        }
    }
}

// ============================================================
// BatchNorm + ReLU -> bf16 h
// ============================================================
__global__ void bn_reduce(const float* __restrict__ X, float* __restrict__ sums) {
    int col  = threadIdx.x & 127;
    int half = threadIdx.x >> 7;
    float s = 0.f, ss = 0.f;
    for (int row = blockIdx.x * 2 + half; row < N_NODES; row += gridDim.x * 2) {
        float v = X[(size_t)row * H_DIM + col];
        s += v; ss += v * v;
    }
    atomicAdd(&sums[col], s);
    atomicAdd(&sums[H_DIM + col], ss);
}

__global__ void bn_apply(const float* __restrict__ X, const float* __restrict__ sums,
                         const float* __restrict__ gg, const float* __restrict__ bb,
                         u16* __restrict__ Hout) {
    __shared__ float sc[H_DIM], sh[H_DIM];
    if (threadIdx.x < H_DIM) {
        float mean = sums[threadIdx.x] * (1.0f / N_NODES);
        float var  = sums[H_DIM + threadIdx.x] * (1.0f / N_NODES) - mean * mean;
        float inv  = rsqrtf(var + BN_EPS) * gg[threadIdx.x];
        sc[threadIdx.x] = inv;
        sh[threadIdx.x] = bb[threadIdx.x] - mean * inv;
    }
    __syncthreads();
    int total = N_NODES * (H_DIM / 4);
    for (int idx = blockIdx.x * 256 + threadIdx.x; idx < total; idx += gridDim.x * 256) {
        float4 v = ((const float4*)X)[idx];
        int c = (idx & 31) << 2;
        ushort4 o;
        o.x = f2bf(fmaxf(v.x * sc[c + 0] + sh[c + 0], 0.f));
        o.y = f2bf(fmaxf(v.y * sc[c + 1] + sh[c + 1], 0.f));
        o.z = f2bf(fmaxf(v.z * sc[c + 2] + sh[c + 2], 0.f));
        o.w = f2bf(fmaxf(v.w * sc[c + 3] + sh[c + 3], 0.f));
        ((ushort4*)Hout)[idx] = o;
    }
}

// ============================================================
// Pool + classifier
// ============================================================
__global__ void pool_kernel(const u16* __restrict__ Hf, const int* __restrict__ batch,
                            float* __restrict__ pool, float* __restrict__ pcnt) {
    int col  = threadIdx.x & 127;
    int half = threadIdx.x >> 7;
    int chunk = (N_NODES + gridDim.x - 1) / gridDim.x;
    int start = blockIdx.x * chunk;
    int end   = min(N_NODES, start + chunk);
    int curg = -1;
    float acc = 0.f, c = 0.f;
    for (int row = start + half; row < end; row += 2) {
        int g = batch[row];
        if (g != curg) {
            if (curg >= 0) {
                atomicAdd(&pool[curg * H_DIM + col], acc);
                if (col == 0) atomicAdd(&pcnt[curg], c);
            }
            curg = g; acc = 0.f; c = 0.f;
        }
        acc += bf2f(Hf[(size_t)row * H_DIM + col]);
        c += 1.f;
    }
    if (curg >= 0) {
        atomicAdd(&pool[curg * H_DIM + col], acc);
        if (col == 0) atomicAdd(&pcnt[curg], c);
    }
}

__global__ void logits_kernel(const float* __restrict__ pool, const float* __restrict__ pcnt,
                              const float* __restrict__ w_out, const float* __restrict__ b_out,
                              float* __restrict__ out) {
    int g = blockIdx.x;
    __shared__ float p[H_DIM];
    float cnt = fmaxf(pcnt[g], 1.0f);
    p[threadIdx.x] = pool[g * H_DIM + threadIdx.x] / cnt;
    __syncthreads();
    if (threadIdx.x < C_CLASSES) {
        float acc = b_out[threadIdx.x];
        for (int k = 0; k < H_DIM; ++k)
            acc += p[k] * w_out[k * C_CLASSES + threadIdx.x];
        out[g * C_CLASSES + threadIdx.x] = 1.0f / (1.0f + expf(-acc));
    }
}

// ============================================================
// Host launch
// ============================================================
static inline size_t align256(size_t x) { return (x + 255) & ~(size_t)255; }

extern "C" void kernel_launch(void* const* d_in, const int* in_sizes, int n_in,
                              void* d_out, int out_size, void* d_ws, size_t ws_size,
                              hipStream_t stream) {
    const float* x      = (const float*)d_in[0];
    const int*   ei     = (const int*)d_in[1];
    const int*   et     = (const int*)d_in[2];
    const int*   batch  = (const int*)d_in[3];
    const float* w_in   = (const float*)d_in[4];
    const float* b_in   = (const float*)d_in[5];
    const float* rel_w  = (const float*)d_in[6];
    const float* root_w = (const float*)d_in[7];
    const float* conv_b = (const float*)d_in[8];
    const float* bn_g   = (const float*)d_in[9];
    const float* bn_b   = (const float*)d_in[10];
    const float* w_out  = (const float*)d_in[11];
    const float* b_out  = (const float*)d_in[12];
    float* out = (float*)d_out;

    char* ws = (char*)d_ws;
    size_t off = 0;
    u16*   h_bf  = (u16*)(ws + off);  off += align256((size_t)N_NODES * H_DIM * 2);
    float* outb  = (float*)(ws + off); off += align256((size_t)N_NODES * H_DIM * 4);
    u16*   x_bf  = (u16*)(ws + off);  off += align256((size_t)N_NODES * F_IN * 2);
    int*   off2  = (int*)(ws + off);  off += align256((size_t)(RN + 1) * 4 + 256);
    int*   cur2  = (int*)(ws + off);  off += align256((size_t)RN * 4);
    int*   e_src = (int*)(ws + off);  off += align256((size_t)E_EDGES * 4 + 256);
    u16*   wp_in   = (u16*)(ws + off); off += align256((size_t)F_IN * H_DIM * 2);
    u16*   wp_root = (u16*)(ws + off); off += align256((size_t)L_LAYERS * H_DIM * H_DIM * 2);
    u16*   wp_rel  = (u16*)(ws + off); off += align256((size_t)L_LAYERS * R_REL * H_DIM * H_DIM * 2);
    int*   scan_part  = (int*)(ws + off); off += align256(2048 * 4);
    float* bn_sums    = (float*)(ws + off); off += align256(2 * H_DIM * 4);
    float* pool       = (float*)(ws + off); off += align256((size_t)G_GRAPHS * H_DIM * 4);
    float* pcnt       = (float*)(ws + off); off += 256;

    // ---- preprocessing: histogram -> scan -> (rel,dst) counting sort ----
    hipMemsetAsync(cur2, 0, (size_t)RN * 4, stream);    // cur2 doubles as histogram
    count_kernel<<<1024, 256, 0, stream>>>(ei, et, cur2);
    const int NB = (RN + 1023) / 1024;                   // 1954
    scan1_kernel<<<NB, 256, 0, stream>>>(cur2, off2, scan_part, RN);
    scan2_kernel<<<1, 256, 0, stream>>>(scan_part, NB);
    scan3_kernel<<<2048, 256, 0, stream>>>(off2, cur2, scan_part, RN);
    finalize_kernel<<<1, 64, 0, stream>>>(off2);
    bucket_kernel<<<2048, 256, 0, stream>>>(ei, et, cur2, e_src);

    // ---- convert inputs / pack weights to bf16 ----
    cvt_bf16_kernel<<<2048, 256, 0, stream>>>(x, x_bf, N_NODES * F_IN / 4);
    pack_w<F_IN><<<1, 256, 0, stream>>>(w_in, wp_in);
    pack_w<H_DIM><<<L_LAYERS, 256, 0, stream>>>(root_w, wp_root);
    pack_w<H_DIM><<<L_LAYERS * R_REL, 256, 0, stream>>>(rel_w, wp_rel);

    // ---- input MLP: h = relu(x @ w_in + b_in) -> bf16 ----
    mfma_dense<F_IN, true, true, true><<<dim3(640), 256, 0, stream>>>(
        x_bf, wp_in, b_in, h_bf, N_NODES);

    // ---- RGCN layers ----
    const int CONV_BLOCKS = (N_NODES + 127) / 128;   // 782
    for (int l = 0; l < L_LAYERS; ++l) {
        // root/self transform + bias -> fp32 outb
        mfma_dense<H_DIM, false, true, false><<<dim3(768), 256, 0, stream>>>(
            h_bf, wp_root + (size_t)l * H_DIM * H_DIM, conv_b + (size_t)l * H_DIM,
            outb, N_NODES);
        // fused aggregate+transform over all 20 relations
        rgcn_conv<<<dim3(CONV_BLOCKS), 512, 0, stream>>>(
            h_bf, wp_rel + (size_t)l * R_REL * H_DIM * H_DIM, e_src, off2, outb);
        // batchnorm + relu -> h
        hipMemsetAsync(bn_sums, 0, 2 * H_DIM * 4, stream);
        bn_reduce<<<512, 256, 0, stream>>>(outb, bn_sums);
        bn_apply<<<2048, 256, 0, stream>>>(outb, bn_sums,
                                           bn_g + (size_t)l * H_DIM,
                                           bn_b + (size_t)l * H_DIM, h_bf);
    }

    // ---- global mean pool + classifier ----
    hipMemsetAsync(pool, 0, (size_t)G_GRAPHS * H_DIM * 4, stream);
    hipMemsetAsync(pcnt, 0, 256, stream);
    pool_kernel<<<512, 256, 0, stream>>>(h_bf, batch, pool, pcnt);
    logits_kernel<<<G_GRAPHS, 128, 0, stream>>>(pool, pcnt, w_out, b_out, out);
}

// Round 5
// 1372.480 us; speedup vs baseline: 4.5632x; 1.0374x over previous
//
#include <hip/hip_runtime.h>

#define N_NODES 100000
#define E_EDGES 1600000
#define F_IN    64
#define H_DIM   128
#define R_REL   20
#define G_GRAPHS 64
#define C_CLASSES 10
#define L_LAYERS 2
#define BN_EPS  1e-5f
#define RN      (R_REL * N_NODES)   // 2,000,000 (rel,dst) bins

typedef unsigned short u16;
typedef unsigned int   u32;
typedef __attribute__((ext_vector_type(8))) short short8;
typedef __attribute__((ext_vector_type(4))) float f32x4;

static __device__ __forceinline__ float bf2f(u16 u) {
    u32 b = ((u32)u) << 16;
    return __builtin_bit_cast(float, b);
}
static __device__ __forceinline__ u16 f2bf(float f) {
    u32 x = __builtin_bit_cast(u32, f);
    u32 r = x + 0x7fff + ((x >> 16) & 1);   // RNE; inputs finite
    return (u16)(r >> 16);
}

// ============================================================
// Edge preprocessing: histogram over (rel,dst), 3-level scan, counting sort
// ============================================================

__global__ void count_kernel(const int* __restrict__ ei, const int* __restrict__ et,
                             int* __restrict__ hist) {
    for (int e = blockIdx.x * blockDim.x + threadIdx.x; e < E_EDGES;
         e += gridDim.x * blockDim.x) {
        int t = et[e];
        int d = ei[E_EDGES + e];
        atomicAdd(&hist[t * N_NODES + d], 1);
    }
}

// exclusive scan, 1024 items / block
__global__ void scan1_kernel(const int* __restrict__ in, int* __restrict__ out,
                             int* __restrict__ part, int n) {
    __shared__ int s[256];
    int t = threadIdx.x;
    int base = blockIdx.x * 1024;
    int v[4]; int sum = 0;
#pragma unroll
    for (int j = 0; j < 4; ++j) {
        int i = base + t * 4 + j;
        v[j] = (i < n) ? in[i] : 0;
        sum += v[j];
    }
    s[t] = sum;
    __syncthreads();
    for (int off = 1; off < 256; off <<= 1) {
        int x = (t >= off) ? s[t - off] : 0;
        __syncthreads();
        s[t] += x;
        __syncthreads();
    }
    if (t == 255) part[blockIdx.x] = s[255];
    int run = s[t] - sum;
#pragma unroll
    for (int j = 0; j < 4; ++j) {
        int i = base + t * 4 + j;
        if (i < n) out[i] = run;
        run += v[j];
    }
}

// exclusive scan of up to 2048 partials in one block (8/thread)
__global__ void scan2_kernel(int* __restrict__ part, int nb) {
    __shared__ int s[256];
    int t = threadIdx.x;
    int loc[8]; int sum = 0;
#pragma unroll
    for (int j = 0; j < 8; ++j) {
        int i = t * 8 + j;
        loc[j] = (i < nb) ? part[i] : 0;
        sum += loc[j];
    }
    s[t] = sum;
    __syncthreads();
    for (int off = 1; off < 256; off <<= 1) {
        int x = (t >= off) ? s[t - off] : 0;
        __syncthreads();
        s[t] += x;
        __syncthreads();
    }
    int run = s[t] - sum;
#pragma unroll
    for (int j = 0; j < 8; ++j) {
        int i = t * 8 + j;
        if (i < nb) part[i] = run;
        run += loc[j];
    }
}

// add block bases; mirror into cur2 (atomic cursors for the sort)
__global__ void scan3_kernel(int* __restrict__ out, int* __restrict__ cur2,
                             const int* __restrict__ part, int n) {
    for (int i = blockIdx.x * blockDim.x + threadIdx.x; i < n;
         i += gridDim.x * blockDim.x) {
        int v = out[i] + part[i >> 10];
        out[i] = v;
        cur2[i] = v;
    }
}

__global__ void finalize_kernel(int* __restrict__ off2) {
    if (threadIdx.x == 0) off2[RN] = E_EDGES;
}

// counting sort into (rel,dst) order; only src index needed downstream
__global__ void bucket_kernel(const int* __restrict__ ei, const int* __restrict__ et,
                              int* __restrict__ cur2, int* __restrict__ esrc) {
    for (int e = blockIdx.x * blockDim.x + threadIdx.x; e < E_EDGES;
         e += gridDim.x * blockDim.x) {
        int t = et[e];
        int s = ei[e];
        int d = ei[E_EDGES + e];
        int pos = atomicAdd(&cur2[t * N_NODES + d], 1);
        esrc[pos] = s;
    }
}

// ============================================================
// Weight pack: fp32 [K,128] -> bf16 MFMA-frag order (verified R2-R4)
// ============================================================
template<int K>
__global__ void pack_w(const float* __restrict__ W, u16* __restrict__ Wp) {
    const float* w = W + (size_t)blockIdx.x * K * H_DIM;
    u16* p = Wp + (size_t)blockIdx.x * K * H_DIM;
    for (int o = threadIdx.x; o < K * H_DIM; o += blockDim.x) {
        int j  = o & 7;
        int l  = (o >> 3) & 63;
        int ct = (o >> 9) & 7;
        int kt = o >> 12;
        int k  = kt * 32 + (l >> 4) * 8 + j;
        int n  = ct * 16 + (l & 15);
        p[o] = f2bf(w[(size_t)k * H_DIM + n]);
    }
}

__global__ void cvt_bf16_kernel(const float* __restrict__ in, u16* __restrict__ out, int n4) {
    for (int i = blockIdx.x * blockDim.x + threadIdx.x; i < n4;
         i += gridDim.x * blockDim.x) {
        float4 v = ((const float4*)in)[i];
        ushort4 o;
        o.x = f2bf(v.x); o.y = f2bf(v.y); o.z = f2bf(v.z); o.w = f2bf(v.w);
        ((ushort4*)out)[i] = o;
    }
}

// ============================================================
// Dense MFMA GEMM (input MLP) — proven R2-R4 structure
// ============================================================
template<int K, bool RELU, bool HASBIAS, bool OUTBF16>
__global__ __launch_bounds__(256)
void mfma_dense(const u16* __restrict__ A, const u16* __restrict__ Wp,
                const float* __restrict__ bias, void* __restrict__ OutV, int M) {
    constexpr int CH = K / 8;
    __shared__ u16 Ws[K * H_DIM];
    __shared__ u16 As[64 * H_DIM];

    for (int o = threadIdx.x; o < K * H_DIM / 8; o += 256)
        ((short8*)Ws)[o] = ((const short8*)Wp)[o];

    const int lane = threadIdx.x & 63;
    const int wave = threadIdx.x >> 6;
    const int l15  = lane & 15;
    const int kgrp = lane >> 4;
    const int arow = wave * 16 + l15;

    for (int tb = blockIdx.x * 64; tb < M; tb += gridDim.x * 64) {
        __syncthreads();
        for (int o = threadIdx.x; o < 64 * CH; o += 256) {
            int row = o / CH, cc = o % CH;
            int grow = tb + row;
            short8 v = {0,0,0,0,0,0,0,0};
            if (grow < M) v = *(const short8*)&A[(size_t)grow * K + cc * 8];
            *(short8*)&As[row * K + ((cc ^ (row & 7)) * 8)] = v;
        }
        __syncthreads();

        f32x4 acc[8];
#pragma unroll
        for (int i = 0; i < 8; ++i) {
            acc[i][0] = 0.f; acc[i][1] = 0.f; acc[i][2] = 0.f; acc[i][3] = 0.f;
        }
#pragma unroll
        for (int kt = 0; kt < K / 32; ++kt) {
            short8 af = *(const short8*)&As[arow * K + (((kt * 4 + kgrp) ^ (arow & 7)) * 8)];
#pragma unroll
            for (int ct = 0; ct < 8; ++ct) {
                short8 bf = *(const short8*)&Ws[(((kt * 8 + ct) * 64) + lane) * 8];
                acc[ct] = __builtin_amdgcn_mfma_f32_16x16x32_bf16(af, bf, acc[ct], 0, 0, 0);
            }
        }

        if (OUTBF16) {
            __syncthreads();
#pragma unroll
            for (int ct = 0; ct < 8; ++ct) {
#pragma unroll
                for (int r = 0; r < 4; ++r) {
                    int row = wave * 16 + kgrp * 4 + r;
                    int col = ct * 16 + l15;
                    float v = acc[ct][r];
                    if (HASBIAS) v += bias[col];
                    if (RELU)    v = fmaxf(v, 0.f);
                    As[row * H_DIM + ((((col >> 3) ^ (row & 7)) << 3) | (col & 7))] = f2bf(v);
                }
            }
            __syncthreads();
            u16* Out = (u16*)OutV;
            for (int o = threadIdx.x; o < 64 * 16; o += 256) {
                int row = o >> 4, cc = o & 15;
                int grow = tb + row;
                if (grow < M)
                    *(short8*)&Out[(size_t)grow * H_DIM + cc * 8] =
                        *(const short8*)&As[row * H_DIM + ((cc ^ (row & 7)) << 3)];
            }
        } else {
            float* Out = (float*)OutV;
#pragma unroll
            for (int ct = 0; ct < 8; ++ct) {
#pragma unroll
                for (int r = 0; r < 4; ++r) {
                    int grow = tb + wave * 16 + kgrp * 4 + r;
                    if (grow < M) {
                        float v = acc[ct][r];
                        if (HASBIAS) v += bias[ct * 16 + l15];
                        if (RELU)    v = fmaxf(v, 0.f);
                        Out[(size_t)grow * H_DIM + ct * 16 + l15] = v;
                    }
                }
            }
        }
    }
}

// ============================================================
// Fused RGCN conv (v2): block owns 128 dst nodes.
// Per relation: 8-way interleaved bin gather (MLP ~8 on the L3-latency
// chain), swizzled LDS A-tile, MFMA accumulated across 20 relations;
// then the root transform as a 21st relation with dense A = h[d0..);
// epilogue: outb = acc + conv_b (plain store, no outb read).
// ============================================================
__global__ __launch_bounds__(512, 4)
void rgcn_conv(const u16* __restrict__ h, const u16* __restrict__ Wrel,
               const u16* __restrict__ Wroot, const float* __restrict__ bias,
               const int* __restrict__ esrc, const int* __restrict__ off2,
               float* __restrict__ outb) {
    __shared__ int offs[R_REL][129];
    __shared__ u16 Ws[H_DIM * H_DIM];      // 32 KB, frag-packed W
    __shared__ u16 Abf[128 * H_DIM];       // 32 KB, swizzled A-tile

    const int d0 = blockIdx.x * 128;
    for (int i = threadIdx.x; i < R_REL * 129; i += 512) {
        int r = i / 129, j = i % 129;
        offs[r][j] = off2[r * N_NODES + min(d0 + j, N_NODES)];
    }

    const int lane = threadIdx.x & 63;
    const int wv   = threadIdx.x >> 6;     // 0..7
    const int l15  = lane & 15;
    const int kgrp = lane >> 4;
    const int arow = wv * 16 + l15;
    const u32* h2 = (const u32*)h;

    f32x4 acc[8];
#pragma unroll
    for (int i = 0; i < 8; ++i) {
        acc[i][0] = 0.f; acc[i][1] = 0.f; acc[i][2] = 0.f; acc[i][3] = 0.f;
    }

    for (int r = 0; r < R_REL; ++r) {
        __syncthreads();   // Ws/Abf free; offs ready (r=0)
        // stage frag-packed W_r (issues early, overlaps the gather below)
        for (int o = threadIdx.x; o < H_DIM * H_DIM / 8; o += 512)
            ((short8*)Ws)[o] = ((const short8*)(Wrel + (size_t)r * H_DIM * H_DIM))[o];

        // aggregate this wave's 16 bins in two 8-interleaved halves
#pragma unroll
        for (int hf = 0; hf < 2; ++hf) {
            const int b0 = wv * 16 + hf * 8;
            int cur[8], end[8];
            float f0[8], f1[8];
#pragma unroll
            for (int bi = 0; bi < 8; ++bi) {
                cur[bi] = offs[r][b0 + bi];
                end[bi] = offs[r][b0 + bi + 1];
                f0[bi] = 0.f; f1[bi] = 0.f;
            }
            while (true) {
                int rem = 0;
#pragma unroll
                for (int bi = 0; bi < 8; ++bi) rem |= (cur[bi] < end[bi]) ? 1 : 0;
                if (!rem) break;
                int sidx[8];
#pragma unroll
                for (int bi = 0; bi < 8; ++bi)
                    if (cur[bi] < end[bi]) sidx[bi] = esrc[cur[bi]];
                u32 row[8];
#pragma unroll
                for (int bi = 0; bi < 8; ++bi)
                    if (cur[bi] < end[bi]) row[bi] = h2[(size_t)sidx[bi] * 64 + lane];
#pragma unroll
                for (int bi = 0; bi < 8; ++bi)
                    if (cur[bi] < end[bi]) {
                        f0[bi] += bf2f((u16)(row[bi] & 0xffff));
                        f1[bi] += bf2f((u16)(row[bi] >> 16));
                        cur[bi]++;
                    }
            }
#pragma unroll
            for (int bi = 0; bi < 8; ++bi) {
                int bin = b0 + bi;
                int c = offs[r][bin + 1] - offs[r][bin];
                float nm = 1.0f / (float)max(c, 1);
                u32 pack = (u32)f2bf(f0[bi] * nm) | ((u32)f2bf(f1[bi] * nm) << 16);
                ((u32*)Abf)[bin * 64 + (((lane >> 2) ^ (bin & 7)) << 2) + (lane & 3)] = pack;
            }
        }
        __syncthreads();   // Abf + Ws visible

#pragma unroll
        for (int kt = 0; kt < 4; ++kt) {
            short8 af = *(const short8*)&Abf[arow * H_DIM + (((kt * 4 + kgrp) ^ (arow & 7)) * 8)];
#pragma unroll
            for (int ct = 0; ct < 8; ++ct) {
                short8 bf = *(const short8*)&Ws[(((kt * 8 + ct) * 64) + lane) * 8];
                acc[ct] = __builtin_amdgcn_mfma_f32_16x16x32_bf16(af, bf, acc[ct], 0, 0, 0);
            }
        }
    }

    // ---- root "relation": dense A = h[d0 .. d0+128) ----
    __syncthreads();
    for (int o = threadIdx.x; o < H_DIM * H_DIM / 8; o += 512)
        ((short8*)Ws)[o] = ((const short8*)Wroot)[o];
    for (int o = threadIdx.x; o < 128 * 16; o += 512) {
        int row = o >> 4, cc = o & 15;
        int grow = d0 + row;
        short8 v = {0,0,0,0,0,0,0,0};
        if (grow < N_NODES) v = *(const short8*)&h[(size_t)grow * H_DIM + cc * 8];
        *(short8*)&Abf[row * H_DIM + ((cc ^ (row & 7)) * 8)] = v;
    }
    __syncthreads();
#pragma unroll
    for (int kt = 0; kt < 4; ++kt) {
        short8 af = *(const short8*)&Abf[arow * H_DIM + (((kt * 4 + kgrp) ^ (arow & 7)) * 8)];
#pragma unroll
        for (int ct = 0; ct < 8; ++ct) {
            short8 bf = *(const short8*)&Ws[(((kt * 8 + ct) * 64) + lane) * 8];
            acc[ct] = __builtin_amdgcn_mfma_f32_16x16x32_bf16(af, bf, acc[ct], 0, 0, 0);
        }
    }

    // ---- epilogue: outb = acc + bias (full overwrite) ----
#pragma unroll
    for (int ct = 0; ct < 8; ++ct) {
        float bv = bias[ct * 16 + l15];
#pragma unroll
        for (int rr = 0; rr < 4; ++rr) {
            int grow = d0 + wv * 16 + kgrp * 4 + rr;
            if (grow < N_NODES)
                outb[(size_t)grow * H_DIM + ct * 16 + l15] = acc[ct][rr] + bv;
        }
    }
}

// ============================================================
// BatchNorm + ReLU -> bf16 h
// ============================================================
__global__ void bn_reduce(const float* __restrict__ X, float* __restrict__ sums) {
    int col  = threadIdx.x & 127;
    int half = threadIdx.x >> 7;
    float s = 0.f, ss = 0.f;
    for (int row = blockIdx.x * 2 + half; row < N_NODES; row += gridDim.x * 2) {
        float v = X[(size_t)row * H_DIM + col];
        s += v; ss += v * v;
    }
    atomicAdd(&sums[col], s);
    atomicAdd(&sums[H_DIM + col], ss);
}

__global__ void bn_apply(const float* __restrict__ X, const float* __restrict__ sums,
                         const float* __restrict__ gg, const float* __restrict__ bb,
                         u16* __restrict__ Hout) {
    __shared__ float sc[H_DIM], sh[H_DIM];
    if (threadIdx.x < H_DIM) {
        float mean = sums[threadIdx.x] * (1.0f / N_NODES);
        float var  = sums[H_DIM + threadIdx.x] * (1.0f / N_NODES) - mean * mean;
        float inv  = rsqrtf(var + BN_EPS) * gg[threadIdx.x];
        sc[threadIdx.x] = inv;
        sh[threadIdx.x] = bb[threadIdx.x] - mean * inv;
    }
    __syncthreads();
    int total = N_NODES * (H_DIM / 4);
    for (int idx = blockIdx.x * 256 + threadIdx.x; idx < total; idx += gridDim.x * 256) {
        float4 v = ((const float4*)X)[idx];
        int c = (idx & 31) << 2;
        ushort4 o;
        o.x = f2bf(fmaxf(v.x * sc[c + 0] + sh[c + 0], 0.f));
        o.y = f2bf(fmaxf(v.y * sc[c + 1] + sh[c + 1], 0.f));
        o.z = f2bf(fmaxf(v.z * sc[c + 2] + sh[c + 2], 0.f));
        o.w = f2bf(fmaxf(v.w * sc[c + 3] + sh[c + 3], 0.f));
        ((ushort4*)Hout)[idx] = o;
    }
}

// ============================================================
// Pool + classifier
// ============================================================
__global__ void pool_kernel(const u16* __restrict__ Hf, const int* __restrict__ batch,
                            float* __restrict__ pool, float* __restrict__ pcnt) {
    int col  = threadIdx.x & 127;
    int half = threadIdx.x >> 7;
    int chunk = (N_NODES + gridDim.x - 1) / gridDim.x;
    int start = blockIdx.x * chunk;
    int end   = min(N_NODES, start + chunk);
    int curg = -1;
    float acc = 0.f, c = 0.f;
    for (int row = start + half; row < end; row += 2) {
        int g = batch[row];
        if (g != curg) {
            if (curg >= 0) {
                atomicAdd(&pool[curg * H_DIM + col], acc);
                if (col == 0) atomicAdd(&pcnt[curg], c);
            }
            curg = g; acc = 0.f; c = 0.f;
        }
        acc += bf2f(Hf[(size_t)row * H_DIM + col]);
        c += 1.f;
    }
    if (curg >= 0) {
        atomicAdd(&pool[curg * H_DIM + col], acc);
        if (col == 0) atomicAdd(&pcnt[curg], c);
    }
}

__global__ void logits_kernel(const float* __restrict__ pool, const float* __restrict__ pcnt,
                              const float* __restrict__ w_out, const float* __restrict__ b_out,
                              float* __restrict__ out) {
    int g = blockIdx.x;
    __shared__ float p[H_DIM];
    float cnt = fmaxf(pcnt[g], 1.0f);
    p[threadIdx.x] = pool[g * H_DIM + threadIdx.x] / cnt;
    __syncthreads();
    if (threadIdx.x < C_CLASSES) {
        float acc = b_out[threadIdx.x];
        for (int k = 0; k < H_DIM; ++k)
            acc += p[k] * w_out[k * C_CLASSES + threadIdx.x];
        out[g * C_CLASSES + threadIdx.x] = 1.0f / (1.0f + expf(-acc));
    }
}

// ============================================================
// Host launch
// ============================================================
static inline size_t align256(size_t x) { return (x + 255) & ~(size_t)255; }

extern "C" void kernel_launch(void* const* d_in, const int* in_sizes, int n_in,
                              void* d_out, int out_size, void* d_ws, size_t ws_size,
                              hipStream_t stream) {
    const float* x      = (const float*)d_in[0];
    const int*   ei     = (const int*)d_in[1];
    const int*   et     = (const int*)d_in[2];
    const int*   batch  = (const int*)d_in[3];
    const float* w_in   = (const float*)d_in[4];
    const float* b_in   = (const float*)d_in[5];
    const float* rel_w  = (const float*)d_in[6];
    const float* root_w = (const float*)d_in[7];
    const float* conv_b = (const float*)d_in[8];
    const float* bn_g   = (const float*)d_in[9];
    const float* bn_b   = (const float*)d_in[10];
    const float* w_out  = (const float*)d_in[11];
    const float* b_out  = (const float*)d_in[12];
    float* out = (float*)d_out;

    char* ws = (char*)d_ws;
    size_t off = 0;
    u16*   h_bf  = (u16*)(ws + off);  off += align256((size_t)N_NODES * H_DIM * 2);
    float* outb  = (float*)(ws + off); off += align256((size_t)N_NODES * H_DIM * 4);
    u16*   x_bf  = (u16*)(ws + off);  off += align256((size_t)N_NODES * F_IN * 2);
    int*   off2  = (int*)(ws + off);  off += align256((size_t)(RN + 1) * 4 + 256);
    int*   cur2  = (int*)(ws + off);  off += align256((size_t)RN * 4);
    int*   e_src = (int*)(ws + off);  off += align256((size_t)E_EDGES * 4 + 256);
    u16*   wp_in   = (u16*)(ws + off); off += align256((size_t)F_IN * H_DIM * 2);
    u16*   wp_root = (u16*)(ws + off); off += align256((size_t)L_LAYERS * H_DIM * H_DIM * 2);
    u16*   wp_rel  = (u16*)(ws + off); off += align256((size_t)L_LAYERS * R_REL * H_DIM * H_DIM * 2);
    int*   scan_part  = (int*)(ws + off); off += align256(2048 * 4);
    float* bn_sums    = (float*)(ws + off); off += align256(2 * H_DIM * 4);
    float* pool       = (float*)(ws + off); off += align256((size_t)G_GRAPHS * H_DIM * 4);
    float* pcnt       = (float*)(ws + off); off += 256;

    // ---- preprocessing: histogram -> scan -> (rel,dst) counting sort ----
    hipMemsetAsync(cur2, 0, (size_t)RN * 4, stream);    // cur2 doubles as histogram
    count_kernel<<<1024, 256, 0, stream>>>(ei, et, cur2);
    const int NB = (RN + 1023) / 1024;                   // 1954
    scan1_kernel<<<NB, 256, 0, stream>>>(cur2, off2, scan_part, RN);
    scan2_kernel<<<1, 256, 0, stream>>>(scan_part, NB);
    scan3_kernel<<<2048, 256, 0, stream>>>(off2, cur2, scan_part, RN);
    finalize_kernel<<<1, 64, 0, stream>>>(off2);
    bucket_kernel<<<2048, 256, 0, stream>>>(ei, et, cur2, e_src);

    // ---- convert inputs / pack weights to bf16 ----
    cvt_bf16_kernel<<<2048, 256, 0, stream>>>(x, x_bf, N_NODES * F_IN / 4);
    pack_w<F_IN><<<1, 256, 0, stream>>>(w_in, wp_in);
    pack_w<H_DIM><<<L_LAYERS, 256, 0, stream>>>(root_w, wp_root);
    pack_w<H_DIM><<<L_LAYERS * R_REL, 256, 0, stream>>>(rel_w, wp_rel);

    // ---- input MLP: h = relu(x @ w_in + b_in) -> bf16 ----
    mfma_dense<F_IN, true, true, true><<<dim3(640), 256, 0, stream>>>(
        x_bf, wp_in, b_in, h_bf, N_NODES);

    // ---- RGCN layers (root transform folded into the conv) ----
    const int CONV_BLOCKS = (N_NODES + 127) / 128;   // 782
    for (int l = 0; l < L_LAYERS; ++l) {
        rgcn_conv<<<dim3(CONV_BLOCKS), 512, 0, stream>>>(
            h_bf, wp_rel + (size_t)l * R_REL * H_DIM * H_DIM,
            wp_root + (size_t)l * H_DIM * H_DIM, conv_b + (size_t)l * H_DIM,
            e_src, off2, outb);
        hipMemsetAsync(bn_sums, 0, 2 * H_DIM * 4, stream);
        bn_reduce<<<512, 256, 0, stream>>>(outb, bn_sums);
        bn_apply<<<2048, 256, 0, stream>>>(outb, bn_sums,
                                           bn_g + (size_t)l * H_DIM,
                                           bn_b + (size_t)l * H_DIM, h_bf);
    }

    // ---- global mean pool + classifier ----
    hipMemsetAsync(pool, 0, (size_t)G_GRAPHS * H_DIM * 4, stream);
    hipMemsetAsync(pcnt, 0, 256, stream);
    pool_kernel<<<512, 256, 0, stream>>>(h_bf, batch, pool, pcnt);
    logits_kernel<<<G_GRAPHS, 128, 0, stream>>>(pool, pcnt, w_out, b_out, out);
}